// Round 3
// baseline (1737.988 us; speedup 1.0000x reference)
//
#include <hip/hip_runtime.h>
#include <hip/hip_bf16.h>

#define NN 50000
#define EE 800000
#define HIDD 128
#define NL 4
#define NC 10
#define BN_EPS 1e-5f

// ---------------- runtime dtype detection ----------------
// flags[0]: 1 = float inputs are fp32, 0 = bf16
// flags[1]: 1 = edge_index is int64, 0 = int32
__global__ void k_detect(const void* h, const void* ei, int* flags) {
    __shared__ int wild, zeros;
    if (threadIdx.x == 0) { wild = 0; zeros = 0; }
    __syncthreads();
    int t = threadIdx.x;
    const unsigned short* hb = (const unsigned short*)h;
    int lw = 0;
    for (int i = t; i < 4096; i += 256) {
        unsigned short u = hb[i];
        int e = (u >> 7) & 0xFF;                       // bf16 exponent field
        if ((e >= 0x8F || e == 0) && (u & 0x7FFF) != 0) lw++;  // |x|>=2^16, NaN/inf, or denormal
    }
    atomicAdd(&wild, lw);
    const int* ii = (const int*)ei;
    int lz = 0;
    for (int i = t; i < 512; i += 256)
        if (ii[2 * i + 1] == 0) lz++;                  // int64 high words are 0
    atomicAdd(&zeros, lz);
    __syncthreads();
    if (threadIdx.x == 0) {
        flags[0] = (wild > 256) ? 1 : 0;
        flags[1] = (zeros > 256) ? 1 : 0;
    }
}

__device__ __forceinline__ int edge_at(const void* ei, int i64, long long idx) {
    return i64 ? (int)((const long long*)ei)[idx] : ((const int*)ei)[idx];
}

// generic float-input conversion to fp32
__global__ void k_cvt(const void* src, float* dst, int n, const int* flags) {
    int i = blockIdx.x * 256 + threadIdx.x;
    if (i >= n) return;
    if (flags[0]) dst[i] = ((const float*)src)[i];
    else          dst[i] = (float)((const __hip_bfloat16*)src)[i];
}

// ---------------- graph preprocessing ----------------

__global__ void k_init_counts(int* counts) {
    int i = blockIdx.x * 256 + threadIdx.x;
    if (i < NN) counts[i] = 1;  // self-loop
}

__global__ void k_count_edges(const void* ei, int* counts, const int* flags) {
    int e = blockIdx.x * 256 + threadIdx.x;
    if (e < EE) {
        int d = edge_at(ei, flags[1], (long long)EE + e);
        if ((unsigned)d < NN) atomicAdd(&counts[d], 1);
    }
}

__global__ void k_dinv(const int* counts, float* dinv) {
    int i = blockIdx.x * 256 + threadIdx.x;
    if (i < NN) dinv[i] = rsqrtf((float)counts[i]);
}

// exclusive scan of counts -> offsets (3 kernels, 1024 elems/block)
__global__ void k_scan1(const int* counts, int* offsets, int* bsums) {
    __shared__ int sc[256];
    int tid = threadIdx.x;
    int base = blockIdx.x * 1024 + tid * 4;
    int4 c = {0, 0, 0, 0};
    if (base + 3 < NN) {
        c = *(const int4*)(counts + base);
    } else {
        if (base + 0 < NN) c.x = counts[base];
        if (base + 1 < NN) c.y = counts[base + 1];
        if (base + 2 < NN) c.z = counts[base + 2];
        if (base + 3 < NN) c.w = counts[base + 3];
    }
    int s = c.x + c.y + c.z + c.w;
    sc[tid] = s;
    __syncthreads();
    for (int off = 1; off < 256; off <<= 1) {
        int v = (tid >= off) ? sc[tid - off] : 0;
        __syncthreads();
        sc[tid] += v;
        __syncthreads();
    }
    int excl = sc[tid] - s;
    if (base < NN) {  // offsets buffer has +1024 slack
        int4 o;
        o.x = excl; o.y = excl + c.x; o.z = o.y + c.y; o.w = o.z + c.z;
        *(int4*)(offsets + base) = o;
    }
    if (tid == 255) bsums[blockIdx.x] = sc[255];
}

__global__ void k_scan2(int* bsums, int nb) {
    __shared__ int sc[64];
    int tid = threadIdx.x;  // 64 threads
    int v = (tid < nb) ? bsums[tid] : 0;
    sc[tid] = v;
    __syncthreads();
    for (int off = 1; off < 64; off <<= 1) {
        int u = (tid >= off) ? sc[tid - off] : 0;
        __syncthreads();
        sc[tid] += u;
        __syncthreads();
    }
    if (tid < nb) bsums[tid] = sc[tid] - v;  // exclusive
}

__global__ void k_scan3(int* offsets, const int* bsums) {
    int base = blockIdx.x * 1024 + threadIdx.x * 4;
    if (base < NN) {
        int add = bsums[blockIdx.x];
        int4 o = *(int4*)(offsets + base);
        o.x += add; o.y += add; o.z += add; o.w += add;
        *(int4*)(offsets + base) = o;
    }
}

__global__ void k_fill_edges(const void* ei, const int* offsets, int* cursor,
                             const float* dinv, int* csr_src, float* csr_w,
                             const int* flags) {
    int e = blockIdx.x * 256 + threadIdx.x;
    if (e >= EE) return;
    int i64 = flags[1];
    int s = edge_at(ei, i64, e);
    int d = edge_at(ei, i64, (long long)EE + e);
    if ((unsigned)s >= NN || (unsigned)d >= NN) return;
    int pos = offsets[d] + atomicAdd(&cursor[d], 1);
    csr_src[pos] = s;
    csr_w[pos] = dinv[s] * dinv[d];
}

__global__ void k_fill_loops(const int* offsets, int* cursor, const float* dinv,
                             int* csr_src, float* csr_w) {
    int i = blockIdx.x * 256 + threadIdx.x;
    if (i >= NN) return;
    int pos = offsets[i] + atomicAdd(&cursor[i], 1);
    csr_src[pos] = i;
    float di = dinv[i];
    csr_w[pos] = di * di;
}

// ---------------- GEMM: C[M x 128] = A[M x 128] @ W(fp32 [128][128]) + bias ----------------
// One wave per output row. Lane l owns cols (2l, 2l+1). A-row broadcast via shfl.
__global__ __launch_bounds__(256) void k_gemm_simple(const float* A, const float* W,
                                                     const float* bias, float* C, int M) {
    int r = blockIdx.x * 4 + (threadIdx.x >> 6);
    int lane = threadIdx.x & 63;
    if (r >= M) return;
    float2 a = ((const float2*)(A + (size_t)r * 128))[lane];
    float acc0 = 0.f, acc1 = 0.f;
    for (int k = 0; k < 128; k += 2) {
        float a0 = __shfl(a.x, k >> 1);
        float a1 = __shfl(a.y, k >> 1);
        float2 w0 = ((const float2*)(W + (size_t)k * 128))[lane];
        float2 w1 = ((const float2*)(W + (size_t)(k + 1) * 128))[lane];
        acc0 = fmaf(a0, w0.x, acc0);
        acc1 = fmaf(a0, w0.y, acc1);
        acc0 = fmaf(a1, w1.x, acc0);
        acc1 = fmaf(a1, w1.y, acc1);
    }
    if (bias) { acc0 += bias[lane * 2]; acc1 += bias[lane * 2 + 1]; }
    float2 o; o.x = acc0; o.y = acc1;
    ((float2*)(C + (size_t)r * 128))[lane] = o;
}

// ---------------- aggregation: out[d] = sum_{e: dst=d} x[src_e]*w_e + bias ----------------
__global__ __launch_bounds__(256) void k_agg(const float* x, const int* csr_src,
                                             const float* csr_w, const int* offsets,
                                             const int* counts, const float* bias,
                                             float* out) {
    int node = blockIdx.x * 4 + (threadIdx.x >> 6);  // one wave per dst node
    int lane = threadIdx.x & 63;
    int start = offsets[node], cnt = counts[node];
    float a0 = 0.f, a1 = 0.f;
    for (int i = 0; i < cnt; ++i) {
        int s = csr_src[start + i];   // wave-uniform -> broadcast
        float w = csr_w[start + i];
        if ((unsigned)s >= NN) continue;  // defensive
        float2 v = ((const float2*)(x + (size_t)s * 128))[lane];
        a0 = fmaf(v.x, w, a0);
        a1 = fmaf(v.y, w, a1);
    }
    float2 o;
    o.x = a0 + bias[lane * 2];
    o.y = a1 + bias[lane * 2 + 1];
    ((float2*)(out + (size_t)node * 128))[lane] = o;
}

// ---------------- batchnorm ----------------

__global__ __launch_bounds__(256) void k_bnred(const float* agg, float* stats) {
    __shared__ float ls[256], lss[256];
    int tid = threadIdx.x;
    int col = tid & 127;
    int r = blockIdx.x * 256 + (tid >> 7);
    int rend = min(NN, (int)(blockIdx.x + 1) * 256);
    float s = 0.f, ss = 0.f;
    for (; r < rend; r += 2) {
        float v = agg[(size_t)r * 128 + col];
        s += v;
        ss += v * v;
    }
    ls[tid] = s;
    lss[tid] = ss;
    __syncthreads();
    if (tid < 128) atomicAdd(&stats[col], ls[tid] + ls[tid + 128]);
    else atomicAdd(&stats[128 + col], lss[tid - 128] + lss[tid]);
}

__global__ void k_bnstats(float* stats) {
    int c = threadIdx.x;  // 128 threads
    float mu = stats[c] * (1.f / NN);
    float var = stats[128 + c] * (1.f / NN) - mu * mu;
    var = fmaxf(var, 0.f);
    stats[c] = mu;
    stats[128 + c] = rsqrtf(var + BN_EPS);
}

__global__ void k_bnup(const float* agg, const float* stats, const float* gamma,
                       const float* beta, float* h) {
    int i = blockIdx.x * 256 + threadIdx.x;
    int col = i & 127;
    float v = (agg[i] - stats[col]) * stats[128 + col] * gamma[col] + beta[col];
    h[i] += fmaxf(v, 0.f);  // residual + relu
}

// ---------------- final MLP: out[N x 10] ----------------
__global__ __launch_bounds__(256) void k_mlp(const float* h, const float* Wm,
                                             const float* bm, void* out, const int* flags) {
    __shared__ float Wl[1280];
    __shared__ float bl[16];
    int tid = threadIdx.x;
    for (int i = tid; i < 1280; i += 256) Wl[i] = Wm[i];
    if (tid < 10) bl[tid] = bm[tid];
    __syncthreads();
    int node = blockIdx.x * 4 + (tid >> 6);  // one wave per node
    int lane = tid & 63;
    float h0 = h[(size_t)node * 128 + lane];
    float h1 = h[(size_t)node * 128 + 64 + lane];
    float p[10];
    for (int c = 0; c < 10; ++c)
        p[c] = h0 * Wl[lane * 10 + c] + h1 * Wl[(lane + 64) * 10 + c];
    for (int off = 32; off > 0; off >>= 1)
        for (int c = 0; c < 10; ++c)
            p[c] += __shfl_down(p[c], off);
    if (lane == 0) {
        if (flags[0]) {
            float* o = (float*)out;
            for (int c = 0; c < 10; ++c) o[node * 10 + c] = p[c] + bl[c];
        } else {
            __hip_bfloat16* o = (__hip_bfloat16*)out;
            for (int c = 0; c < 10; ++c) o[node * 10 + c] = __float2bfloat16(p[c] + bl[c]);
        }
    }
}

// ---------------- orchestration ----------------

extern "C" void kernel_launch(void* const* d_in, const int* in_sizes, int n_in,
                              void* d_out, int out_size, void* d_ws, size_t ws_size,
                              hipStream_t stream) {
    const void* h_in = d_in[0];
    const void* ei   = d_in[1];
    const void* Wemb = d_in[3];
    const void* bemb = d_in[4];
    const void* Ws   = d_in[5];
    const void* bs   = d_in[6];
    const void* gam  = d_in[7];
    const void* bet  = d_in[8];
    const void* Wm   = d_in[9];
    const void* bm   = d_in[10];

    char* ws = (char*)d_ws;
    size_t off = 0;
    auto alloc = [&](size_t bytes) -> void* {
        void* p = ws + off;
        off = (off + bytes + 255) & ~(size_t)255;
        return p;
    };
    float* hbuf   = (float*)alloc((size_t)NN * 128 * 4);
    float* xbuf   = (float*)alloc((size_t)NN * 128 * 4);
    float* abuf   = (float*)alloc((size_t)NN * 128 * 4);
    int* counts   = (int*)alloc((size_t)NN * 4);
    int* offsets  = (int*)alloc((size_t)(NN + 1024) * 4);
    int* cursor   = (int*)alloc((size_t)NN * 4);
    int* bsums    = (int*)alloc(64 * 4);
    float* dinv   = (float*)alloc((size_t)NN * 4);
    float* stats  = (float*)alloc(256 * 4);
    int* csr_src  = (int*)alloc((size_t)(EE + NN) * 4);
    float* csr_w  = (float*)alloc((size_t)(EE + NN) * 4);
    int* flags    = (int*)alloc(64);
    float* Wemb_f = (float*)alloc(16384 * 4);
    float* Ws_f   = (float*)alloc(65536 * 4);
    float* bemb_f = (float*)alloc(128 * 4);
    float* bs_f   = (float*)alloc(512 * 4);
    float* gam_f  = (float*)alloc(512 * 4);
    float* bet_f  = (float*)alloc(512 * 4);
    float* Wm_f   = (float*)alloc(1280 * 4);
    float* bm_f   = (float*)alloc(16 * 4);

    k_detect<<<1, 256, 0, stream>>>(h_in, ei, flags);

    // convert all float inputs to fp32 staging
    k_cvt<<<(NN * 128 + 255) / 256, 256, 0, stream>>>(h_in, xbuf, NN * 128, flags);
    k_cvt<<<64, 256, 0, stream>>>(Wemb, Wemb_f, 16384, flags);
    k_cvt<<<256, 256, 0, stream>>>(Ws, Ws_f, 65536, flags);
    k_cvt<<<1, 256, 0, stream>>>(bemb, bemb_f, 128, flags);
    k_cvt<<<2, 256, 0, stream>>>(bs, bs_f, 512, flags);
    k_cvt<<<2, 256, 0, stream>>>(gam, gam_f, 512, flags);
    k_cvt<<<2, 256, 0, stream>>>(bet, bet_f, 512, flags);
    k_cvt<<<5, 256, 0, stream>>>(Wm, Wm_f, 1280, flags);
    k_cvt<<<1, 256, 0, stream>>>(bm, bm_f, 10, flags);

    hipMemsetAsync(cursor, 0, (size_t)NN * 4, stream);
    k_init_counts<<<(NN + 255) / 256, 256, 0, stream>>>(counts);
    k_count_edges<<<(EE + 255) / 256, 256, 0, stream>>>(ei, counts, flags);
    k_dinv<<<(NN + 255) / 256, 256, 0, stream>>>(counts, dinv);
    int nb = (NN + 1023) / 1024;  // 49
    k_scan1<<<nb, 256, 0, stream>>>(counts, offsets, bsums);
    k_scan2<<<1, 64, 0, stream>>>(bsums, nb);
    k_scan3<<<nb, 256, 0, stream>>>(offsets, bsums);
    k_fill_edges<<<(EE + 255) / 256, 256, 0, stream>>>(ei, offsets, cursor, dinv, csr_src, csr_w, flags);
    k_fill_loops<<<(NN + 255) / 256, 256, 0, stream>>>(offsets, cursor, dinv, csr_src, csr_w);

    int gblocks = (NN + 3) / 4;  // 12500
    // embedding: hbuf = h0 @ W_emb + b_emb
    k_gemm_simple<<<gblocks, 256, 0, stream>>>(xbuf, Wemb_f, bemb_f, hbuf, NN);

    for (int l = 0; l < NL; ++l) {
        k_gemm_simple<<<gblocks, 256, 0, stream>>>(hbuf, Ws_f + (size_t)l * 16384, nullptr, xbuf, NN);
        k_agg<<<NN / 4, 256, 0, stream>>>(xbuf, csr_src, csr_w, offsets, counts, bs_f + l * 128, abuf);
        hipMemsetAsync(stats, 0, 256 * 4, stream);
        k_bnred<<<(NN + 255) / 256, 256, 0, stream>>>(abuf, stats);
        k_bnstats<<<1, 128, 0, stream>>>(stats);
        k_bnup<<<(NN * 128) / 256, 256, 0, stream>>>(abuf, stats, gam_f + l * 128, bet_f + l * 128, hbuf);
    }
    k_mlp<<<NN / 4, 256, 0, stream>>>(hbuf, Wm_f, bm_f, d_out, flags);
}

// Round 4
// 1114.298 us; speedup vs baseline: 1.5597x; 1.5597x over previous
//
#include <hip/hip_runtime.h>
#include <hip/hip_bf16.h>

#define NN 50000
#define EE 800000
#define HIDD 128
#define NL 4
#define NC 10
#define BN_EPS 1e-5f

// ---------------- runtime dtype detection ----------------
// flags[0]: 1 = float inputs are fp32, 0 = bf16
// flags[1]: 1 = edge_index is int64, 0 = int32
__global__ void k_detect(const void* h, const void* ei, int* flags) {
    __shared__ int wild, zeros;
    if (threadIdx.x == 0) { wild = 0; zeros = 0; }
    __syncthreads();
    int t = threadIdx.x;
    const unsigned short* hb = (const unsigned short*)h;
    int lw = 0;
    for (int i = t; i < 4096; i += 256) {
        unsigned short u = hb[i];
        int e = (u >> 7) & 0xFF;                       // bf16 exponent field
        if ((e >= 0x8F || e == 0) && (u & 0x7FFF) != 0) lw++;  // |x|>=2^16, NaN/inf, or denormal
    }
    atomicAdd(&wild, lw);
    const int* ii = (const int*)ei;
    int lz = 0;
    for (int i = t; i < 512; i += 256)
        if (ii[2 * i + 1] == 0) lz++;                  // int64 high words are 0
    atomicAdd(&zeros, lz);
    __syncthreads();
    if (threadIdx.x == 0) {
        flags[0] = (wild > 256) ? 1 : 0;
        flags[1] = (zeros > 256) ? 1 : 0;
    }
}

__device__ __forceinline__ int edge_at(const void* ei, int i64, long long idx) {
    return i64 ? (int)((const long long*)ei)[idx] : ((const int*)ei)[idx];
}

// generic float-input conversion to fp32
__global__ void k_cvt(const void* src, float* dst, int n, const int* flags) {
    int i = blockIdx.x * 256 + threadIdx.x;
    if (i >= n) return;
    if (flags[0]) dst[i] = ((const float*)src)[i];
    else          dst[i] = (float)((const __hip_bfloat16*)src)[i];
}

// ---------------- graph preprocessing ----------------

__global__ void k_init_counts(int* counts) {
    int i = blockIdx.x * 256 + threadIdx.x;
    if (i < NN) counts[i] = 1;  // self-loop
}

__global__ void k_count_edges(const void* ei, int* counts, const int* flags) {
    int e = blockIdx.x * 256 + threadIdx.x;
    if (e < EE) {
        int d = edge_at(ei, flags[1], (long long)EE + e);
        if ((unsigned)d < NN) atomicAdd(&counts[d], 1);
    }
}

__global__ void k_dinv(const int* counts, float* dinv) {
    int i = blockIdx.x * 256 + threadIdx.x;
    if (i < NN) dinv[i] = rsqrtf((float)counts[i]);
}

// exclusive scan of counts -> offsets (3 kernels, 1024 elems/block)
__global__ void k_scan1(const int* counts, int* offsets, int* bsums) {
    __shared__ int sc[256];
    int tid = threadIdx.x;
    int base = blockIdx.x * 1024 + tid * 4;
    int4 c = {0, 0, 0, 0};
    if (base + 3 < NN) {
        c = *(const int4*)(counts + base);
    } else {
        if (base + 0 < NN) c.x = counts[base];
        if (base + 1 < NN) c.y = counts[base + 1];
        if (base + 2 < NN) c.z = counts[base + 2];
        if (base + 3 < NN) c.w = counts[base + 3];
    }
    int s = c.x + c.y + c.z + c.w;
    sc[tid] = s;
    __syncthreads();
    for (int off = 1; off < 256; off <<= 1) {
        int v = (tid >= off) ? sc[tid - off] : 0;
        __syncthreads();
        sc[tid] += v;
        __syncthreads();
    }
    int excl = sc[tid] - s;
    if (base < NN) {  // offsets buffer has +1024 slack
        int4 o;
        o.x = excl; o.y = excl + c.x; o.z = o.y + c.y; o.w = o.z + c.z;
        *(int4*)(offsets + base) = o;
    }
    if (tid == 255) bsums[blockIdx.x] = sc[255];
}

__global__ void k_scan2(int* bsums, int nb) {
    __shared__ int sc[64];
    int tid = threadIdx.x;  // 64 threads
    int v = (tid < nb) ? bsums[tid] : 0;
    sc[tid] = v;
    __syncthreads();
    for (int off = 1; off < 64; off <<= 1) {
        int u = (tid >= off) ? sc[tid - off] : 0;
        __syncthreads();
        sc[tid] += u;
        __syncthreads();
    }
    if (tid < nb) bsums[tid] = sc[tid] - v;  // exclusive
}

__global__ void k_scan3(int* offsets, const int* bsums) {
    int base = blockIdx.x * 1024 + threadIdx.x * 4;
    if (base < NN) {
        int add = bsums[blockIdx.x];
        int4 o = *(int4*)(offsets + base);
        o.x += add; o.y += add; o.z += add; o.w += add;
        *(int4*)(offsets + base) = o;
    }
}

__global__ void k_fill_edges(const void* ei, const int* offsets, int* cursor,
                             const float* dinv, int* csr_src, float* csr_w,
                             const int* flags) {
    int e = blockIdx.x * 256 + threadIdx.x;
    if (e >= EE) return;
    int i64 = flags[1];
    int s = edge_at(ei, i64, e);
    int d = edge_at(ei, i64, (long long)EE + e);
    if ((unsigned)s >= NN || (unsigned)d >= NN) return;
    int pos = offsets[d] + atomicAdd(&cursor[d], 1);
    csr_src[pos] = s;
    csr_w[pos] = dinv[s] * dinv[d];
}

__global__ void k_fill_loops(const int* offsets, int* cursor, const float* dinv,
                             int* csr_src, float* csr_w) {
    int i = blockIdx.x * 256 + threadIdx.x;
    if (i >= NN) return;
    int pos = offsets[i] + atomicAdd(&cursor[i], 1);
    csr_src[pos] = i;
    float di = dinv[i];
    csr_w[pos] = di * di;
}

// ---------------- GEMM: C[M x 128] = A[M x 128] @ W(fp32 [128][128]) + bias ----------------
// 128x128 output tile per block, 8x8 outputs per thread, A^T staged in LDS.
__global__ __launch_bounds__(256, 2) void k_gemm_tiled(const float* __restrict__ A,
                                                       const float* __restrict__ W,
                                                       const float* __restrict__ bias,
                                                       float* __restrict__ C, int M) {
    __shared__ float At[32][132];  // k-slice x rows; stride 132: 16B-aligned rows, <=4-way write conflict
    int tid = threadIdx.x;
    int tx = tid & 15, ty = tid >> 4;
    int r0 = blockIdx.x * 128;
    float acc[8][8];
#pragma unroll
    for (int i = 0; i < 8; ++i)
#pragma unroll
        for (int j = 0; j < 8; ++j) acc[i][j] = 0.f;

    for (int k0 = 0; k0 < 128; k0 += 32) {
        // stage A[r0..r0+127][k0..k0+31] transposed into At[k][row]
#pragma unroll
        for (int j = 0; j < 4; ++j) {
            int f = tid + j * 256;        // 0..1023 float4 slots
            int row = f >> 3, kq = f & 7; // 8 float4 per row
            float4 v = make_float4(0.f, 0.f, 0.f, 0.f);
            int gr = r0 + row;
            if (gr < M) v = *(const float4*)(A + (size_t)gr * 128 + k0 + kq * 4);
            At[kq * 4 + 0][row] = v.x;
            At[kq * 4 + 1][row] = v.y;
            At[kq * 4 + 2][row] = v.z;
            At[kq * 4 + 3][row] = v.w;
        }
        __syncthreads();
#pragma unroll 4
        for (int k = 0; k < 32; ++k) {
            float4 a0 = *(const float4*)&At[k][ty * 8];
            float4 a1 = *(const float4*)&At[k][ty * 8 + 4];
            const float* wr = W + (size_t)(k0 + k) * 128 + tx * 8;
            float4 w0 = *(const float4*)wr;
            float4 w1 = *(const float4*)(wr + 4);
            float a[8] = {a0.x, a0.y, a0.z, a0.w, a1.x, a1.y, a1.z, a1.w};
            float w[8] = {w0.x, w0.y, w0.z, w0.w, w1.x, w1.y, w1.z, w1.w};
#pragma unroll
            for (int i = 0; i < 8; ++i)
#pragma unroll
                for (int j = 0; j < 8; ++j)
                    acc[i][j] = fmaf(a[i], w[j], acc[i][j]);
        }
        __syncthreads();
    }
    // epilogue
    float badd[8];
#pragma unroll
    for (int j = 0; j < 8; ++j) badd[j] = bias ? bias[tx * 8 + j] : 0.f;
#pragma unroll
    for (int i = 0; i < 8; ++i) {
        int gr = r0 + ty * 8 + i;
        if (gr >= M) break;
        float4 o0, o1;
        o0.x = acc[i][0] + badd[0]; o0.y = acc[i][1] + badd[1];
        o0.z = acc[i][2] + badd[2]; o0.w = acc[i][3] + badd[3];
        o1.x = acc[i][4] + badd[4]; o1.y = acc[i][5] + badd[5];
        o1.z = acc[i][6] + badd[6]; o1.w = acc[i][7] + badd[7];
        float* cr = C + (size_t)gr * 128 + tx * 8;
        *(float4*)cr = o0;
        *(float4*)(cr + 4) = o1;
    }
}

// ---------------- aggregation: out[d] = sum_{e: dst=d} x[src_e]*w_e + bias ----------------
__global__ __launch_bounds__(256) void k_agg(const float* x, const int* csr_src,
                                             const float* csr_w, const int* offsets,
                                             const int* counts, const float* bias,
                                             float* out) {
    int node = blockIdx.x * 4 + (threadIdx.x >> 6);  // one wave per dst node
    int lane = threadIdx.x & 63;
    int start = offsets[node], cnt = counts[node];
    float a0 = 0.f, a1 = 0.f;
    for (int i = 0; i < cnt; ++i) {
        int s = csr_src[start + i];   // wave-uniform -> broadcast
        float w = csr_w[start + i];
        if ((unsigned)s >= NN) continue;  // defensive
        float2 v = ((const float2*)(x + (size_t)s * 128))[lane];
        a0 = fmaf(v.x, w, a0);
        a1 = fmaf(v.y, w, a1);
    }
    float2 o;
    o.x = a0 + bias[lane * 2];
    o.y = a1 + bias[lane * 2 + 1];
    ((float2*)(out + (size_t)node * 128))[lane] = o;
}

// ---------------- batchnorm ----------------

__global__ __launch_bounds__(256) void k_bnred(const float* agg, float* stats) {
    __shared__ float ls[256], lss[256];
    int tid = threadIdx.x;
    int col = tid & 127;
    int r = blockIdx.x * 256 + (tid >> 7);
    int rend = min(NN, (int)(blockIdx.x + 1) * 256);
    float s = 0.f, ss = 0.f;
    for (; r < rend; r += 2) {
        float v = agg[(size_t)r * 128 + col];
        s += v;
        ss += v * v;
    }
    ls[tid] = s;
    lss[tid] = ss;
    __syncthreads();
    if (tid < 128) atomicAdd(&stats[col], ls[tid] + ls[tid + 128]);
    else atomicAdd(&stats[128 + col], lss[tid - 128] + lss[tid]);
}

__global__ void k_bnstats(float* stats) {
    int c = threadIdx.x;  // 128 threads
    float mu = stats[c] * (1.f / NN);
    float var = stats[128 + c] * (1.f / NN) - mu * mu;
    var = fmaxf(var, 0.f);
    stats[c] = mu;
    stats[128 + c] = rsqrtf(var + BN_EPS);
}

__global__ void k_bnup(const float* agg, const float* stats, const float* gamma,
                       const float* beta, float* h) {
    int i = blockIdx.x * 256 + threadIdx.x;
    int col = i & 127;
    float v = (agg[i] - stats[col]) * stats[128 + col] * gamma[col] + beta[col];
    h[i] += fmaxf(v, 0.f);  // residual + relu
}

// ---------------- final MLP: out[N x 10] ----------------
__global__ __launch_bounds__(256) void k_mlp(const float* h, const float* Wm,
                                             const float* bm, void* out, const int* flags) {
    __shared__ float Wl[1280];
    __shared__ float bl[16];
    int tid = threadIdx.x;
    for (int i = tid; i < 1280; i += 256) Wl[i] = Wm[i];
    if (tid < 10) bl[tid] = bm[tid];
    __syncthreads();
    int node = blockIdx.x * 4 + (tid >> 6);  // one wave per node
    int lane = tid & 63;
    float h0 = h[(size_t)node * 128 + lane];
    float h1 = h[(size_t)node * 128 + 64 + lane];
    float p[10];
    for (int c = 0; c < 10; ++c)
        p[c] = h0 * Wl[lane * 10 + c] + h1 * Wl[(lane + 64) * 10 + c];
    for (int off = 32; off > 0; off >>= 1)
        for (int c = 0; c < 10; ++c)
            p[c] += __shfl_down(p[c], off);
    if (lane == 0) {
        if (flags[0]) {
            float* o = (float*)out;
            for (int c = 0; c < 10; ++c) o[node * 10 + c] = p[c] + bl[c];
        } else {
            __hip_bfloat16* o = (__hip_bfloat16*)out;
            for (int c = 0; c < 10; ++c) o[node * 10 + c] = __float2bfloat16(p[c] + bl[c]);
        }
    }
}

// ---------------- orchestration ----------------

extern "C" void kernel_launch(void* const* d_in, const int* in_sizes, int n_in,
                              void* d_out, int out_size, void* d_ws, size_t ws_size,
                              hipStream_t stream) {
    const void* h_in = d_in[0];
    const void* ei   = d_in[1];
    const void* Wemb = d_in[3];
    const void* bemb = d_in[4];
    const void* Ws   = d_in[5];
    const void* bs   = d_in[6];
    const void* gam  = d_in[7];
    const void* bet  = d_in[8];
    const void* Wm   = d_in[9];
    const void* bm   = d_in[10];

    char* ws = (char*)d_ws;
    size_t off = 0;
    auto alloc = [&](size_t bytes) -> void* {
        void* p = ws + off;
        off = (off + bytes + 255) & ~(size_t)255;
        return p;
    };
    float* hbuf   = (float*)alloc((size_t)NN * 128 * 4);
    float* xbuf   = (float*)alloc((size_t)NN * 128 * 4);
    float* abuf   = (float*)alloc((size_t)NN * 128 * 4);
    int* counts   = (int*)alloc((size_t)NN * 4);
    int* offsets  = (int*)alloc((size_t)(NN + 1024) * 4);
    int* cursor   = (int*)alloc((size_t)NN * 4);
    int* bsums    = (int*)alloc(64 * 4);
    float* dinv   = (float*)alloc((size_t)NN * 4);
    float* stats  = (float*)alloc(256 * 4);
    int* csr_src  = (int*)alloc((size_t)(EE + NN) * 4);
    float* csr_w  = (float*)alloc((size_t)(EE + NN) * 4);
    int* flags    = (int*)alloc(64);
    float* Wemb_f = (float*)alloc(16384 * 4);
    float* Ws_f   = (float*)alloc(65536 * 4);
    float* bemb_f = (float*)alloc(128 * 4);
    float* bs_f   = (float*)alloc(512 * 4);
    float* gam_f  = (float*)alloc(512 * 4);
    float* bet_f  = (float*)alloc(512 * 4);
    float* Wm_f   = (float*)alloc(1280 * 4);
    float* bm_f   = (float*)alloc(16 * 4);

    k_detect<<<1, 256, 0, stream>>>(h_in, ei, flags);

    // convert all float inputs to fp32 staging
    k_cvt<<<(NN * 128 + 255) / 256, 256, 0, stream>>>(h_in, xbuf, NN * 128, flags);
    k_cvt<<<64, 256, 0, stream>>>(Wemb, Wemb_f, 16384, flags);
    k_cvt<<<256, 256, 0, stream>>>(Ws, Ws_f, 65536, flags);
    k_cvt<<<1, 256, 0, stream>>>(bemb, bemb_f, 128, flags);
    k_cvt<<<2, 256, 0, stream>>>(bs, bs_f, 512, flags);
    k_cvt<<<2, 256, 0, stream>>>(gam, gam_f, 512, flags);
    k_cvt<<<2, 256, 0, stream>>>(bet, bet_f, 512, flags);
    k_cvt<<<5, 256, 0, stream>>>(Wm, Wm_f, 1280, flags);
    k_cvt<<<1, 256, 0, stream>>>(bm, bm_f, 10, flags);

    hipMemsetAsync(cursor, 0, (size_t)NN * 4, stream);
    k_init_counts<<<(NN + 255) / 256, 256, 0, stream>>>(counts);
    k_count_edges<<<(EE + 255) / 256, 256, 0, stream>>>(ei, counts, flags);
    k_dinv<<<(NN + 255) / 256, 256, 0, stream>>>(counts, dinv);
    int nb = (NN + 1023) / 1024;  // 49
    k_scan1<<<nb, 256, 0, stream>>>(counts, offsets, bsums);
    k_scan2<<<1, 64, 0, stream>>>(bsums, nb);
    k_scan3<<<nb, 256, 0, stream>>>(offsets, bsums);
    k_fill_edges<<<(EE + 255) / 256, 256, 0, stream>>>(ei, offsets, cursor, dinv, csr_src, csr_w, flags);
    k_fill_loops<<<(NN + 255) / 256, 256, 0, stream>>>(offsets, cursor, dinv, csr_src, csr_w);

    int gblocks = (NN + 127) / 128;  // 391
    // embedding: hbuf = h0 @ W_emb + b_emb
    k_gemm_tiled<<<gblocks, 256, 0, stream>>>(xbuf, Wemb_f, bemb_f, hbuf, NN);

    for (int l = 0; l < NL; ++l) {
        k_gemm_tiled<<<gblocks, 256, 0, stream>>>(hbuf, Ws_f + (size_t)l * 16384, nullptr, xbuf, NN);
        k_agg<<<NN / 4, 256, 0, stream>>>(xbuf, csr_src, csr_w, offsets, counts, bs_f + l * 128, abuf);
        hipMemsetAsync(stats, 0, 256 * 4, stream);
        k_bnred<<<(NN + 255) / 256, 256, 0, stream>>>(abuf, stats);
        k_bnstats<<<1, 128, 0, stream>>>(stats);
        k_bnup<<<(NN * 128) / 256, 256, 0, stream>>>(abuf, stats, gam_f + l * 128, bet_f + l * 128, hbuf);
    }
    k_mlp<<<NN / 4, 256, 0, stream>>>(hbuf, Wm_f, bm_f, d_out, flags);
}

// Round 5
// 934.586 us; speedup vs baseline: 1.8596x; 1.1923x over previous
//
#include <hip/hip_runtime.h>
#include <hip/hip_bf16.h>

#define NN 50000
#define EE 800000
#define HIDD 128
#define NL 4
#define NC 10
#define BN_EPS 1e-5f

// ---------------- runtime dtype detection ----------------
// flags[0]: 1 = float inputs are fp32, 0 = bf16
// flags[1]: 1 = edge_index is int64, 0 = int32
__global__ void k_detect(const void* h, const void* ei, int* flags) {
    __shared__ int wild, zeros;
    if (threadIdx.x == 0) { wild = 0; zeros = 0; }
    __syncthreads();
    int t = threadIdx.x;
    const unsigned short* hb = (const unsigned short*)h;
    int lw = 0;
    for (int i = t; i < 4096; i += 256) {
        unsigned short u = hb[i];
        int e = (u >> 7) & 0xFF;                       // bf16 exponent field
        if ((e >= 0x8F || e == 0) && (u & 0x7FFF) != 0) lw++;  // |x|>=2^16, NaN/inf, denormal
    }
    atomicAdd(&wild, lw);
    const int* ii = (const int*)ei;
    int lz = 0;
    for (int i = t; i < 512; i += 256)
        if (ii[2 * i + 1] == 0) lz++;                  // int64 high words are 0
    atomicAdd(&zeros, lz);
    __syncthreads();
    if (threadIdx.x == 0) {
        flags[0] = (wild > 256) ? 1 : 0;
        flags[1] = (zeros > 256) ? 1 : 0;
    }
}

__device__ __forceinline__ int edge_at(const void* ei, int i64, long long idx) {
    return i64 ? (int)((const long long*)ei)[idx] : ((const int*)ei)[idx];
}

// generic float-input conversion to fp32
__global__ void k_cvt(const void* src, float* dst, int n, const int* flags) {
    int i = blockIdx.x * 256 + threadIdx.x;
    if (i >= n) return;
    if (flags[0]) dst[i] = ((const float*)src)[i];
    else          dst[i] = (float)((const __hip_bfloat16*)src)[i];
}

// ---------------- graph preprocessing ----------------

__global__ void k_init_counts(int* counts) {
    int i = blockIdx.x * 256 + threadIdx.x;
    if (i < NN) counts[i] = 1;  // self-loop
}

__global__ void k_count_edges(const void* ei, int* counts, const int* flags) {
    int e = blockIdx.x * 256 + threadIdx.x;
    if (e < EE) {
        int d = edge_at(ei, flags[1], (long long)EE + e);
        if ((unsigned)d < NN) atomicAdd(&counts[d], 1);
    }
}

__global__ void k_dinv(const int* counts, float* dinv) {
    int i = blockIdx.x * 256 + threadIdx.x;
    if (i < NN) dinv[i] = rsqrtf((float)counts[i]);
}

// exclusive scan of counts -> offsets (3 kernels, 1024 elems/block)
__global__ void k_scan1(const int* counts, int* offsets, int* bsums) {
    __shared__ int sc[256];
    int tid = threadIdx.x;
    int base = blockIdx.x * 1024 + tid * 4;
    int4 c = {0, 0, 0, 0};
    if (base + 3 < NN) {
        c = *(const int4*)(counts + base);
    } else {
        if (base + 0 < NN) c.x = counts[base];
        if (base + 1 < NN) c.y = counts[base + 1];
        if (base + 2 < NN) c.z = counts[base + 2];
        if (base + 3 < NN) c.w = counts[base + 3];
    }
    int s = c.x + c.y + c.z + c.w;
    sc[tid] = s;
    __syncthreads();
    for (int off = 1; off < 256; off <<= 1) {
        int v = (tid >= off) ? sc[tid - off] : 0;
        __syncthreads();
        sc[tid] += v;
        __syncthreads();
    }
    int excl = sc[tid] - s;
    if (base < NN) {
        int4 o;
        o.x = excl; o.y = excl + c.x; o.z = o.y + c.y; o.w = o.z + c.z;
        *(int4*)(offsets + base) = o;
    }
    if (tid == 255) bsums[blockIdx.x] = sc[255];
}

__global__ void k_scan2(int* bsums, int nb) {
    __shared__ int sc[64];
    int tid = threadIdx.x;  // 64 threads
    int v = (tid < nb) ? bsums[tid] : 0;
    sc[tid] = v;
    __syncthreads();
    for (int off = 1; off < 64; off <<= 1) {
        int u = (tid >= off) ? sc[tid - off] : 0;
        __syncthreads();
        sc[tid] += u;
        __syncthreads();
    }
    if (tid < nb) bsums[tid] = sc[tid] - v;  // exclusive
}

__global__ void k_scan3(int* offsets, const int* bsums) {
    int base = blockIdx.x * 1024 + threadIdx.x * 4;
    if (base < NN) {
        int add = bsums[blockIdx.x];
        int4 o = *(int4*)(offsets + base);
        o.x += add; o.y += add; o.z += add; o.w += add;
        *(int4*)(offsets + base) = o;
    }
}

// csr_pack[pos] = {src, float_bits(norm)}
__global__ void k_fill_edges(const void* ei, const int* offsets, int* cursor,
                             const float* dinv, int2* csr_pack, const int* flags) {
    int e = blockIdx.x * 256 + threadIdx.x;
    if (e >= EE) return;
    int i64 = flags[1];
    int s = edge_at(ei, i64, e);
    int d = edge_at(ei, i64, (long long)EE + e);
    if ((unsigned)s >= NN || (unsigned)d >= NN) return;
    int pos = offsets[d] + atomicAdd(&cursor[d], 1);
    int2 p; p.x = s; p.y = __float_as_int(dinv[s] * dinv[d]);
    csr_pack[pos] = p;
}

__global__ void k_fill_loops(const int* offsets, int* cursor, const float* dinv,
                             int2* csr_pack) {
    int i = blockIdx.x * 256 + threadIdx.x;
    if (i >= NN) return;
    int pos = offsets[i] + atomicAdd(&cursor[i], 1);
    float di = dinv[i];
    int2 p; p.x = i; p.y = __float_as_int(di * di);
    csr_pack[pos] = p;
}

// ---------------- GEMM: C[M x 128] = A[M x 128] @ W(fp32 [128][128]) + bias ----------------
// 128x128 output tile per block, 8x8 outputs per thread, A^T staged in LDS.
// If Cb != null, write bf16 output (for the gather-bound aggregation); else fp32 C.
__global__ __launch_bounds__(256, 2) void k_gemm_tiled(const float* __restrict__ A,
                                                       const float* __restrict__ W,
                                                       const float* __restrict__ bias,
                                                       float* __restrict__ C,
                                                       unsigned short* __restrict__ Cb,
                                                       int M) {
    __shared__ float At[32][132];
    int tid = threadIdx.x;
    int tx = tid & 15, ty = tid >> 4;
    int r0 = blockIdx.x * 128;
    float acc[8][8];
#pragma unroll
    for (int i = 0; i < 8; ++i)
#pragma unroll
        for (int j = 0; j < 8; ++j) acc[i][j] = 0.f;

    for (int k0 = 0; k0 < 128; k0 += 32) {
#pragma unroll
        for (int j = 0; j < 4; ++j) {
            int f = tid + j * 256;
            int row = f >> 3, kq = f & 7;
            float4 v = make_float4(0.f, 0.f, 0.f, 0.f);
            int gr = r0 + row;
            if (gr < M) v = *(const float4*)(A + (size_t)gr * 128 + k0 + kq * 4);
            At[kq * 4 + 0][row] = v.x;
            At[kq * 4 + 1][row] = v.y;
            At[kq * 4 + 2][row] = v.z;
            At[kq * 4 + 3][row] = v.w;
        }
        __syncthreads();
#pragma unroll 4
        for (int k = 0; k < 32; ++k) {
            float4 a0 = *(const float4*)&At[k][ty * 8];
            float4 a1 = *(const float4*)&At[k][ty * 8 + 4];
            const float* wr = W + (size_t)(k0 + k) * 128 + tx * 8;
            float4 w0 = *(const float4*)wr;
            float4 w1 = *(const float4*)(wr + 4);
            float a[8] = {a0.x, a0.y, a0.z, a0.w, a1.x, a1.y, a1.z, a1.w};
            float w[8] = {w0.x, w0.y, w0.z, w0.w, w1.x, w1.y, w1.z, w1.w};
#pragma unroll
            for (int i = 0; i < 8; ++i)
#pragma unroll
                for (int j = 0; j < 8; ++j)
                    acc[i][j] = fmaf(a[i], w[j], acc[i][j]);
        }
        __syncthreads();
    }
    float badd[8];
#pragma unroll
    for (int j = 0; j < 8; ++j) badd[j] = bias ? bias[tx * 8 + j] : 0.f;
#pragma unroll
    for (int i = 0; i < 8; ++i) {
        int gr = r0 + ty * 8 + i;
        if (gr >= M) break;
        float v[8];
#pragma unroll
        for (int j = 0; j < 8; ++j) v[j] = acc[i][j] + badd[j];
        if (Cb) {
            union { unsigned short us[8]; uint4 u4; } pk;
#pragma unroll
            for (int j = 0; j < 8; ++j)
                pk.us[j] = __bfloat16_as_ushort(__float2bfloat16(v[j]));
            *(uint4*)(Cb + (size_t)gr * 128 + tx * 8) = pk.u4;
        } else {
            float4 o0, o1;
            o0.x = v[0]; o0.y = v[1]; o0.z = v[2]; o0.w = v[3];
            o1.x = v[4]; o1.y = v[5]; o1.z = v[6]; o1.w = v[7];
            float* cr = C + (size_t)gr * 128 + tx * 8;
            *(float4*)cr = o0;
            *(float4*)(cr + 4) = o1;
        }
    }
}

// ---------------- aggregation: out[d] = sum_{e: dst=d} x[src_e]*w_e + bias ----------------
// x rows are bf16 (256 B). One wave per dst node; lane owns cols {2l, 2l+1}.
__global__ __launch_bounds__(256) void k_agg(const unsigned int* __restrict__ xb,
                                             const int2* __restrict__ csr_pack,
                                             const int* __restrict__ offsets,
                                             const int* __restrict__ counts,
                                             const float* __restrict__ bias,
                                             float* __restrict__ out) {
    int node = blockIdx.x * 4 + (threadIdx.x >> 6);
    int lane = threadIdx.x & 63;
    int start = offsets[node], cnt = counts[node];
    float a0 = 0.f, a1 = 0.f;
    for (int base = 0; base < cnt; base += 64) {
        int2 p = make_int2(0, 0);
        if (base + lane < cnt) p = csr_pack[start + base + lane];
        int m = min(64, cnt - base);
        for (int j = 0; j < m; ++j) {
            int s = __shfl(p.x, j);
            float w = __int_as_float(__shfl(p.y, j));
            unsigned int u = xb[s * 64 + lane];           // 2 bf16: cols 2l, 2l+1
            float f0 = __uint_as_float(u << 16);
            float f1 = __uint_as_float(u & 0xFFFF0000u);
            a0 = fmaf(f0, w, a0);
            a1 = fmaf(f1, w, a1);
        }
    }
    float2 o;
    o.x = a0 + bias[lane * 2];
    o.y = a1 + bias[lane * 2 + 1];
    ((float2*)(out + (size_t)node * 128))[lane] = o;
}

// ---------------- batchnorm ----------------

__global__ __launch_bounds__(256) void k_bnred(const float* agg, float* stats) {
    __shared__ float ls[256], lss[256];
    int tid = threadIdx.x;
    int col = tid & 127;
    int r = blockIdx.x * 256 + (tid >> 7);
    int rend = min(NN, (int)(blockIdx.x + 1) * 256);
    float s = 0.f, ss = 0.f;
    for (; r < rend; r += 2) {
        float v = agg[(size_t)r * 128 + col];
        s += v;
        ss += v * v;
    }
    ls[tid] = s;
    lss[tid] = ss;
    __syncthreads();
    if (tid < 128) atomicAdd(&stats[col], ls[tid] + ls[tid + 128]);
    else atomicAdd(&stats[128 + col], lss[tid - 128] + lss[tid]);
}

__global__ void k_bnstats(float* stats) {
    int c = threadIdx.x;  // 128 threads
    float mu = stats[c] * (1.f / NN);
    float var = stats[128 + c] * (1.f / NN) - mu * mu;
    var = fmaxf(var, 0.f);
    stats[c] = mu;
    stats[128 + c] = rsqrtf(var + BN_EPS);
}

__global__ void k_bnup(const float* agg, const float* stats, const float* gamma,
                       const float* beta, float* h) {
    int i = blockIdx.x * 256 + threadIdx.x;
    int col = i & 127;
    float v = (agg[i] - stats[col]) * stats[128 + col] * gamma[col] + beta[col];
    h[i] += fmaxf(v, 0.f);  // residual + relu
}

// ---------------- final MLP: out[N x 10] ----------------
__global__ __launch_bounds__(256) void k_mlp(const float* h, const float* Wm,
                                             const float* bm, void* out, const int* flags) {
    __shared__ float Wl[1280];
    __shared__ float bl[16];
    int tid = threadIdx.x;
    for (int i = tid; i < 1280; i += 256) Wl[i] = Wm[i];
    if (tid < 10) bl[tid] = bm[tid];
    __syncthreads();
    int node = blockIdx.x * 4 + (tid >> 6);
    int lane = tid & 63;
    float h0 = h[(size_t)node * 128 + lane];
    float h1 = h[(size_t)node * 128 + 64 + lane];
    float p[10];
    for (int c = 0; c < 10; ++c)
        p[c] = h0 * Wl[lane * 10 + c] + h1 * Wl[(lane + 64) * 10 + c];
    for (int off = 32; off > 0; off >>= 1)
        for (int c = 0; c < 10; ++c)
            p[c] += __shfl_down(p[c], off);
    if (lane == 0) {
        if (flags[0]) {
            float* o = (float*)out;
            for (int c = 0; c < 10; ++c) o[node * 10 + c] = p[c] + bl[c];
        } else {
            __hip_bfloat16* o = (__hip_bfloat16*)out;
            for (int c = 0; c < 10; ++c) o[node * 10 + c] = __float2bfloat16(p[c] + bl[c]);
        }
    }
}

// ---------------- orchestration ----------------

extern "C" void kernel_launch(void* const* d_in, const int* in_sizes, int n_in,
                              void* d_out, int out_size, void* d_ws, size_t ws_size,
                              hipStream_t stream) {
    const void* h_in = d_in[0];
    const void* ei   = d_in[1];
    const void* Wemb = d_in[3];
    const void* bemb = d_in[4];
    const void* Ws   = d_in[5];
    const void* bs   = d_in[6];
    const void* gam  = d_in[7];
    const void* bet  = d_in[8];
    const void* Wm   = d_in[9];
    const void* bm   = d_in[10];

    char* ws = (char*)d_ws;
    size_t off = 0;
    auto alloc = [&](size_t bytes) -> void* {
        void* p = ws + off;
        off = (off + bytes + 255) & ~(size_t)255;
        return p;
    };
    float* hbuf    = (float*)alloc((size_t)NN * 128 * 4);
    float* abuf    = (float*)alloc((size_t)NN * 128 * 4);
    unsigned int* xb = (unsigned int*)alloc((size_t)NN * 64 * 4);  // bf16 x, 256 B/row
    float* x0      = (float*)alloc((size_t)NN * 128 * 4);          // fp32 input copy
    int* counts    = (int*)alloc((size_t)NN * 4);
    int* offsets   = (int*)alloc((size_t)(NN + 1024) * 4);
    int* cursor    = (int*)alloc((size_t)NN * 4);
    int* bsums     = (int*)alloc(64 * 4);
    float* dinv    = (float*)alloc((size_t)NN * 4);
    float* stats   = (float*)alloc(256 * 4);
    int2* csr_pack = (int2*)alloc((size_t)(EE + NN) * 8);
    int* flags     = (int*)alloc(64);
    float* Wemb_f  = (float*)alloc(16384 * 4);
    float* Ws_f    = (float*)alloc(65536 * 4);
    float* bemb_f  = (float*)alloc(128 * 4);
    float* bs_f    = (float*)alloc(512 * 4);
    float* gam_f   = (float*)alloc(512 * 4);
    float* bet_f   = (float*)alloc(512 * 4);
    float* Wm_f    = (float*)alloc(1280 * 4);
    float* bm_f    = (float*)alloc(16 * 4);

    k_detect<<<1, 256, 0, stream>>>(h_in, ei, flags);

    k_cvt<<<(NN * 128 + 255) / 256, 256, 0, stream>>>(h_in, x0, NN * 128, flags);
    k_cvt<<<64, 256, 0, stream>>>(Wemb, Wemb_f, 16384, flags);
    k_cvt<<<256, 256, 0, stream>>>(Ws, Ws_f, 65536, flags);
    k_cvt<<<1, 256, 0, stream>>>(bemb, bemb_f, 128, flags);
    k_cvt<<<2, 256, 0, stream>>>(bs, bs_f, 512, flags);
    k_cvt<<<2, 256, 0, stream>>>(gam, gam_f, 512, flags);
    k_cvt<<<2, 256, 0, stream>>>(bet, bet_f, 512, flags);
    k_cvt<<<5, 256, 0, stream>>>(Wm, Wm_f, 1280, flags);
    k_cvt<<<1, 256, 0, stream>>>(bm, bm_f, 10, flags);

    hipMemsetAsync(cursor, 0, (size_t)NN * 4, stream);
    k_init_counts<<<(NN + 255) / 256, 256, 0, stream>>>(counts);
    k_count_edges<<<(EE + 255) / 256, 256, 0, stream>>>(ei, counts, flags);
    k_dinv<<<(NN + 255) / 256, 256, 0, stream>>>(counts, dinv);
    int nb = (NN + 1023) / 1024;  // 49
    k_scan1<<<nb, 256, 0, stream>>>(counts, offsets, bsums);
    k_scan2<<<1, 64, 0, stream>>>(bsums, nb);
    k_scan3<<<nb, 256, 0, stream>>>(offsets, bsums);
    k_fill_edges<<<(EE + 255) / 256, 256, 0, stream>>>(ei, offsets, cursor, dinv, csr_pack, flags);
    k_fill_loops<<<(NN + 255) / 256, 256, 0, stream>>>(offsets, cursor, dinv, csr_pack);

    int gblocks = (NN + 127) / 128;  // 391
    // embedding: hbuf = h0 @ W_emb + b_emb  (fp32 out)
    k_gemm_tiled<<<gblocks, 256, 0, stream>>>(x0, Wemb_f, bemb_f, hbuf, nullptr, NN);

    for (int l = 0; l < NL; ++l) {
        // x = h @ W_l  (bf16 out, feeds gather)
        k_gemm_tiled<<<gblocks, 256, 0, stream>>>(hbuf, Ws_f + (size_t)l * 16384, nullptr,
                                                  nullptr, (unsigned short*)xb, NN);
        k_agg<<<NN / 4, 256, 0, stream>>>(xb, csr_pack, offsets, counts, bs_f + l * 128, abuf);
        hipMemsetAsync(stats, 0, 256 * 4, stream);
        k_bnred<<<(NN + 255) / 256, 256, 0, stream>>>(abuf, stats);
        k_bnstats<<<1, 128, 0, stream>>>(stats);
        k_bnup<<<(NN * 128) / 256, 256, 0, stream>>>(abuf, stats, gam_f + l * 128, bet_f + l * 128, hbuf);
    }
    k_mlp<<<NN / 4, 256, 0, stream>>>(hbuf, Wm_f, bm_f, d_out, flags);
}

// Round 6
// 757.814 us; speedup vs baseline: 2.2934x; 1.2333x over previous
//
#include <hip/hip_runtime.h>
#include <hip/hip_bf16.h>

#define NN 50000
#define EE 800000
#define HIDD 128
#define NL 4
#define NC 10
#define BN_EPS 1e-5f

typedef __bf16 bf16x8 __attribute__((ext_vector_type(8)));
typedef float f32x4 __attribute__((ext_vector_type(4)));

// ---------------- runtime dtype detection ----------------
// flags[0]: 1 = float inputs are fp32, 0 = bf16
// flags[1]: 1 = edge_index is int64, 0 = int32
__global__ void k_detect(const void* h, const void* ei, int* flags) {
    __shared__ int wild, zeros;
    if (threadIdx.x == 0) { wild = 0; zeros = 0; }
    __syncthreads();
    int t = threadIdx.x;
    const unsigned short* hb = (const unsigned short*)h;
    int lw = 0;
    for (int i = t; i < 4096; i += 256) {
        unsigned short u = hb[i];
        int e = (u >> 7) & 0xFF;
        if ((e >= 0x8F || e == 0) && (u & 0x7FFF) != 0) lw++;
    }
    atomicAdd(&wild, lw);
    const int* ii = (const int*)ei;
    int lz = 0;
    for (int i = t; i < 512; i += 256)
        if (ii[2 * i + 1] == 0) lz++;
    atomicAdd(&zeros, lz);
    __syncthreads();
    if (threadIdx.x == 0) {
        flags[0] = (wild > 256) ? 1 : 0;
        flags[1] = (zeros > 256) ? 1 : 0;
    }
}

__device__ __forceinline__ int edge_at(const void* ei, int i64, long long idx) {
    return i64 ? (int)((const long long*)ei)[idx] : ((const int*)ei)[idx];
}

__global__ void k_cvt(const void* src, float* dst, int n, const int* flags) {
    int i = blockIdx.x * 256 + threadIdx.x;
    if (i >= n) return;
    if (flags[0]) dst[i] = ((const float*)src)[i];
    else          dst[i] = (float)((const __hip_bfloat16*)src)[i];
}

// ---------------- graph preprocessing ----------------

__global__ void k_init_counts(int* counts) {
    int i = blockIdx.x * 256 + threadIdx.x;
    if (i < NN) counts[i] = 1;  // self-loop
}

__global__ void k_count_edges(const void* ei, int* counts, const int* flags) {
    int e = blockIdx.x * 256 + threadIdx.x;
    if (e < EE) {
        int d = edge_at(ei, flags[1], (long long)EE + e);
        if ((unsigned)d < NN) atomicAdd(&counts[d], 1);
    }
}

__global__ void k_dinv(const int* counts, float* dinv) {
    int i = blockIdx.x * 256 + threadIdx.x;
    if (i < NN) dinv[i] = rsqrtf((float)counts[i]);
}

__global__ void k_scan1(const int* counts, int* offsets, int* bsums) {
    __shared__ int sc[256];
    int tid = threadIdx.x;
    int base = blockIdx.x * 1024 + tid * 4;
    int4 c = {0, 0, 0, 0};
    if (base + 3 < NN) {
        c = *(const int4*)(counts + base);
    } else {
        if (base + 0 < NN) c.x = counts[base];
        if (base + 1 < NN) c.y = counts[base + 1];
        if (base + 2 < NN) c.z = counts[base + 2];
        if (base + 3 < NN) c.w = counts[base + 3];
    }
    int s = c.x + c.y + c.z + c.w;
    sc[tid] = s;
    __syncthreads();
    for (int off = 1; off < 256; off <<= 1) {
        int v = (tid >= off) ? sc[tid - off] : 0;
        __syncthreads();
        sc[tid] += v;
        __syncthreads();
    }
    int excl = sc[tid] - s;
    if (base < NN) {
        int4 o;
        o.x = excl; o.y = excl + c.x; o.z = o.y + c.y; o.w = o.z + c.z;
        *(int4*)(offsets + base) = o;
    }
    if (tid == 255) bsums[blockIdx.x] = sc[255];
}

__global__ void k_scan2(int* bsums, int nb) {
    __shared__ int sc[64];
    int tid = threadIdx.x;
    int v = (tid < nb) ? bsums[tid] : 0;
    sc[tid] = v;
    __syncthreads();
    for (int off = 1; off < 64; off <<= 1) {
        int u = (tid >= off) ? sc[tid - off] : 0;
        __syncthreads();
        sc[tid] += u;
        __syncthreads();
    }
    if (tid < nb) bsums[tid] = sc[tid] - v;
}

__global__ void k_scan3(int* offsets, const int* bsums) {
    int base = blockIdx.x * 1024 + threadIdx.x * 4;
    if (base < NN) {
        int add = bsums[blockIdx.x];
        int4 o = *(int4*)(offsets + base);
        o.x += add; o.y += add; o.z += add; o.w += add;
        *(int4*)(offsets + base) = o;
    }
}

__global__ void k_fill_edges(const void* ei, const int* offsets, int* cursor,
                             const float* dinv, int2* csr_pack, const int* flags) {
    int e = blockIdx.x * 256 + threadIdx.x;
    if (e >= EE) return;
    int i64 = flags[1];
    int s = edge_at(ei, i64, e);
    int d = edge_at(ei, i64, (long long)EE + e);
    if ((unsigned)s >= NN || (unsigned)d >= NN) return;
    int pos = offsets[d] + atomicAdd(&cursor[d], 1);
    int2 p; p.x = s; p.y = __float_as_int(dinv[s] * dinv[d]);
    csr_pack[pos] = p;
}

__global__ void k_fill_loops(const int* offsets, int* cursor, const float* dinv,
                             int2* csr_pack) {
    int i = blockIdx.x * 256 + threadIdx.x;
    if (i >= NN) return;
    int pos = offsets[i] + atomicAdd(&cursor[i], 1);
    float di = dinv[i];
    int2 p; p.x = i; p.y = __float_as_int(di * di);
    csr_pack[pos] = p;
}

// ---------------- weight packing into MFMA B-fragment order (hi/lo planes) ----------------
// Bpack[(kt*8+nt)*64 + lane][j] = W[kt*32 + (lane>>4)*8 + j][nt*16 + (lane&15)]
__global__ void k_pack(const float* Wemb, const float* Ws, __bf16* Bhi, __bf16* Blo) {
    int idx = blockIdx.x * 256 + threadIdx.x;
    if (idx >= 5 * 16384) return;
    int m = idx >> 14, r = idx & 16383;
    int kt = r >> 12, nt = (r >> 9) & 7, lane = (r >> 3) & 63, j = r & 7;
    int k = kt * 32 + (lane >> 4) * 8 + j;
    int n = nt * 16 + (lane & 15);
    const float* W = (m == 0) ? Wemb : (Ws + (size_t)(m - 1) * 16384);
    float w = W[k * 128 + n];
    __bf16 hi = (__bf16)w;
    Bhi[idx] = hi;
    Blo[idx] = (__bf16)(w - (float)hi);
}

// ---------------- MFMA GEMM: C[M x 128] = A[M x 128] @ W + bias ----------------
// 64-row tile/block, 4 waves x 16 rows. A split hi/lo bf16 in LDS; 3-term product
// (AhiBhi + AloBhi + AhiBlo) ~ fp32 accuracy. Cb!=null -> bf16 output.
__global__ __launch_bounds__(256) void k_gemm_mfma(const float* __restrict__ A,
                                                   const __bf16* __restrict__ Bhi,
                                                   const __bf16* __restrict__ Blo,
                                                   const float* __restrict__ bias,
                                                   float* __restrict__ C,
                                                   __hip_bfloat16* __restrict__ Cb,
                                                   int M) {
    __shared__ __bf16 a_hi[64][136];  // +8 pad: 16B-aligned rows, 2-way-max bank alias
    __shared__ __bf16 a_lo[64][136];
    int tid = threadIdx.x;
    int r0 = blockIdx.x * 64;
    int cq = tid & 31;   // float4 index within row
    int rb = tid >> 5;   // 0..7
#pragma unroll
    for (int p = 0; p < 8; ++p) {
        int r = rb + p * 8;
        int gr = r0 + r;
        float4 v = make_float4(0.f, 0.f, 0.f, 0.f);
        if (gr < M) v = ((const float4*)(A + (size_t)gr * 128))[cq];
        float f[4] = {v.x, v.y, v.z, v.w};
        int cb = cq * 4;
#pragma unroll
        for (int t = 0; t < 4; ++t) {
            __bf16 hi = (__bf16)f[t];
            a_hi[r][cb + t] = hi;
            a_lo[r][cb + t] = (__bf16)(f[t] - (float)hi);
        }
    }
    __syncthreads();
    int lane = tid & 63, wave = tid >> 6;
    int quad = lane >> 4, l15 = lane & 15;
    int rw = wave * 16;
    f32x4 acc[8];
#pragma unroll
    for (int nt = 0; nt < 8; ++nt) acc[nt] = (f32x4){0.f, 0.f, 0.f, 0.f};
#pragma unroll
    for (int kt = 0; kt < 4; ++kt) {
        int k0 = kt * 32 + quad * 8;
        bf16x8 ah = *(const bf16x8*)&a_hi[rw + l15][k0];
        bf16x8 al = *(const bf16x8*)&a_lo[rw + l15][k0];
#pragma unroll
        for (int nt = 0; nt < 8; ++nt) {
            size_t boff = (((size_t)(kt * 8 + nt) * 64 + lane) * 8);
            bf16x8 bh = *(const bf16x8*)(Bhi + boff);
            bf16x8 bl = *(const bf16x8*)(Blo + boff);
            acc[nt] = __builtin_amdgcn_mfma_f32_16x16x32_bf16(ah, bh, acc[nt], 0, 0, 0);
            acc[nt] = __builtin_amdgcn_mfma_f32_16x16x32_bf16(al, bh, acc[nt], 0, 0, 0);
            acc[nt] = __builtin_amdgcn_mfma_f32_16x16x32_bf16(ah, bl, acc[nt], 0, 0, 0);
        }
    }
    // epilogue: C/D layout col = nt*16 + l15, row = rw + quad*4 + reg
#pragma unroll
    for (int nt = 0; nt < 8; ++nt) {
        int col = nt * 16 + l15;
        float badd = bias ? bias[col] : 0.f;
#pragma unroll
        for (int reg = 0; reg < 4; ++reg) {
            int gr = r0 + rw + quad * 4 + reg;
            if (gr < M) {
                float v = acc[nt][reg] + badd;
                if (Cb) Cb[(size_t)gr * 128 + col] = __float2bfloat16(v);
                else    C[(size_t)gr * 128 + col] = v;
            }
        }
    }
}

// ---------------- aggregation: out[d] = sum_{e: dst=d} x[src_e]*w_e + bias ----------------
// x rows bf16 (256 B). One wave per dst node; 2-edge unroll for 2x in-flight loads.
__global__ __launch_bounds__(256) void k_agg(const unsigned int* __restrict__ xb,
                                             const int2* __restrict__ csr_pack,
                                             const int* __restrict__ offsets,
                                             const int* __restrict__ counts,
                                             const float* __restrict__ bias,
                                             float* __restrict__ out) {
    int node = blockIdx.x * 4 + (threadIdx.x >> 6);
    int lane = threadIdx.x & 63;
    int start = offsets[node], cnt = counts[node];
    float a0 = 0.f, a1 = 0.f, b0 = 0.f, b1 = 0.f;
    for (int base = 0; base < cnt; base += 64) {
        int2 p = make_int2(0, 0);
        if (base + lane < cnt) p = csr_pack[start + base + lane];
        int m = min(64, cnt - base);
        int j = 0;
        for (; j + 2 <= m; j += 2) {
            int s0 = __shfl(p.x, j);
            float w0 = __int_as_float(__shfl(p.y, j));
            int s1 = __shfl(p.x, j + 1);
            float w1 = __int_as_float(__shfl(p.y, j + 1));
            unsigned int u0 = xb[s0 * 64 + lane];
            unsigned int u1 = xb[s1 * 64 + lane];
            a0 = fmaf(__uint_as_float(u0 << 16), w0, a0);
            a1 = fmaf(__uint_as_float(u0 & 0xFFFF0000u), w0, a1);
            b0 = fmaf(__uint_as_float(u1 << 16), w1, b0);
            b1 = fmaf(__uint_as_float(u1 & 0xFFFF0000u), w1, b1);
        }
        if (j < m) {
            int s0 = __shfl(p.x, j);
            float w0 = __int_as_float(__shfl(p.y, j));
            unsigned int u0 = xb[s0 * 64 + lane];
            a0 = fmaf(__uint_as_float(u0 << 16), w0, a0);
            a1 = fmaf(__uint_as_float(u0 & 0xFFFF0000u), w0, a1);
        }
    }
    float2 o;
    o.x = a0 + b0 + bias[lane * 2];
    o.y = a1 + b1 + bias[lane * 2 + 1];
    ((float2*)(out + (size_t)node * 128))[lane] = o;
}

// ---------------- batchnorm ----------------

__global__ __launch_bounds__(256) void k_bnred(const float* agg, float* stats) {
    __shared__ float ls[256], lss[256];
    int tid = threadIdx.x;
    int col = tid & 127;
    int r = blockIdx.x * 256 + (tid >> 7);
    int rend = min(NN, (int)(blockIdx.x + 1) * 256);
    float s = 0.f, ss = 0.f;
    for (; r < rend; r += 2) {
        float v = agg[(size_t)r * 128 + col];
        s += v;
        ss += v * v;
    }
    ls[tid] = s;
    lss[tid] = ss;
    __syncthreads();
    if (tid < 128) atomicAdd(&stats[col], ls[tid] + ls[tid + 128]);
    else atomicAdd(&stats[128 + col], lss[tid - 128] + lss[tid]);
}

__global__ void k_bnstats(float* stats) {
    int c = threadIdx.x;  // 128 threads
    float mu = stats[c] * (1.f / NN);
    float var = stats[128 + c] * (1.f / NN) - mu * mu;
    var = fmaxf(var, 0.f);
    stats[c] = mu;
    stats[128 + c] = rsqrtf(var + BN_EPS);
}

__global__ void k_bnup(const float* agg, const float* stats, const float* gamma,
                       const float* beta, float* h) {
    int i = blockIdx.x * 256 + threadIdx.x;
    int col = i & 127;
    float v = (agg[i] - stats[col]) * stats[128 + col] * gamma[col] + beta[col];
    h[i] += fmaxf(v, 0.f);  // residual + relu
}

// ---------------- final MLP: out[N x 10] ----------------
__global__ __launch_bounds__(256) void k_mlp(const float* h, const float* Wm,
                                             const float* bm, void* out, const int* flags) {
    __shared__ float Wl[1280];
    __shared__ float bl[16];
    int tid = threadIdx.x;
    for (int i = tid; i < 1280; i += 256) Wl[i] = Wm[i];
    if (tid < 10) bl[tid] = bm[tid];
    __syncthreads();
    int node = blockIdx.x * 4 + (tid >> 6);
    int lane = tid & 63;
    float h0 = h[(size_t)node * 128 + lane];
    float h1 = h[(size_t)node * 128 + 64 + lane];
    float p[10];
    for (int c = 0; c < 10; ++c)
        p[c] = h0 * Wl[lane * 10 + c] + h1 * Wl[(lane + 64) * 10 + c];
    for (int off = 32; off > 0; off >>= 1)
        for (int c = 0; c < 10; ++c)
            p[c] += __shfl_down(p[c], off);
    if (lane == 0) {
        if (flags[0]) {
            float* o = (float*)out;
            for (int c = 0; c < 10; ++c) o[node * 10 + c] = p[c] + bl[c];
        } else {
            __hip_bfloat16* o = (__hip_bfloat16*)out;
            for (int c = 0; c < 10; ++c) o[node * 10 + c] = __float2bfloat16(p[c] + bl[c]);
        }
    }
}

// ---------------- orchestration ----------------

extern "C" void kernel_launch(void* const* d_in, const int* in_sizes, int n_in,
                              void* d_out, int out_size, void* d_ws, size_t ws_size,
                              hipStream_t stream) {
    const void* h_in = d_in[0];
    const void* ei   = d_in[1];
    const void* Wemb = d_in[3];
    const void* bemb = d_in[4];
    const void* Ws   = d_in[5];
    const void* bs   = d_in[6];
    const void* gam  = d_in[7];
    const void* bet  = d_in[8];
    const void* Wm   = d_in[9];
    const void* bm   = d_in[10];

    char* ws = (char*)d_ws;
    size_t off = 0;
    auto alloc = [&](size_t bytes) -> void* {
        void* p = ws + off;
        off = (off + bytes + 255) & ~(size_t)255;
        return p;
    };
    float* hbuf    = (float*)alloc((size_t)NN * 128 * 4);
    float* abuf    = (float*)alloc((size_t)NN * 128 * 4);
    unsigned int* xb = (unsigned int*)alloc((size_t)NN * 64 * 4);  // bf16 x, 256 B/row
    float* x0      = (float*)alloc((size_t)NN * 128 * 4);          // fp32 input copy
    int* counts    = (int*)alloc((size_t)NN * 4);
    int* offsets   = (int*)alloc((size_t)(NN + 1024) * 4);
    int* cursor    = (int*)alloc((size_t)NN * 4);
    int* bsums     = (int*)alloc(64 * 4);
    float* dinv    = (float*)alloc((size_t)NN * 4);
    float* stats   = (float*)alloc(256 * 4);
    int2* csr_pack = (int2*)alloc((size_t)(EE + NN) * 8);
    int* flags     = (int*)alloc(64);
    float* Wemb_f  = (float*)alloc(16384 * 4);
    float* Ws_f    = (float*)alloc(65536 * 4);
    float* bemb_f  = (float*)alloc(128 * 4);
    float* bs_f    = (float*)alloc(512 * 4);
    float* gam_f   = (float*)alloc(512 * 4);
    float* bet_f   = (float*)alloc(512 * 4);
    float* Wm_f    = (float*)alloc(1280 * 4);
    float* bm_f    = (float*)alloc(16 * 4);
    __bf16* Bhi    = (__bf16*)alloc((size_t)5 * 16384 * 2);
    __bf16* Blo    = (__bf16*)alloc((size_t)5 * 16384 * 2);

    k_detect<<<1, 256, 0, stream>>>(h_in, ei, flags);

    k_cvt<<<(NN * 128 + 255) / 256, 256, 0, stream>>>(h_in, x0, NN * 128, flags);
    k_cvt<<<64, 256, 0, stream>>>(Wemb, Wemb_f, 16384, flags);
    k_cvt<<<256, 256, 0, stream>>>(Ws, Ws_f, 65536, flags);
    k_cvt<<<1, 256, 0, stream>>>(bemb, bemb_f, 128, flags);
    k_cvt<<<2, 256, 0, stream>>>(bs, bs_f, 512, flags);
    k_cvt<<<2, 256, 0, stream>>>(gam, gam_f, 512, flags);
    k_cvt<<<2, 256, 0, stream>>>(bet, bet_f, 512, flags);
    k_cvt<<<5, 256, 0, stream>>>(Wm, Wm_f, 1280, flags);
    k_cvt<<<1, 256, 0, stream>>>(bm, bm_f, 10, flags);

    k_pack<<<(5 * 16384 + 255) / 256, 256, 0, stream>>>(Wemb_f, Ws_f, Bhi, Blo);

    hipMemsetAsync(cursor, 0, (size_t)NN * 4, stream);
    k_init_counts<<<(NN + 255) / 256, 256, 0, stream>>>(counts);
    k_count_edges<<<(EE + 255) / 256, 256, 0, stream>>>(ei, counts, flags);
    k_dinv<<<(NN + 255) / 256, 256, 0, stream>>>(counts, dinv);
    int nb = (NN + 1023) / 1024;  // 49
    k_scan1<<<nb, 256, 0, stream>>>(counts, offsets, bsums);
    k_scan2<<<1, 64, 0, stream>>>(bsums, nb);
    k_scan3<<<nb, 256, 0, stream>>>(offsets, bsums);
    k_fill_edges<<<(EE + 255) / 256, 256, 0, stream>>>(ei, offsets, cursor, dinv, csr_pack, flags);
    k_fill_loops<<<(NN + 255) / 256, 256, 0, stream>>>(offsets, cursor, dinv, csr_pack);

    int gblocks = (NN + 63) / 64;  // 782
    // embedding: hbuf = x0 @ W_emb + b_emb  (fp32 out)
    k_gemm_mfma<<<gblocks, 256, 0, stream>>>(x0, Bhi, Blo, bemb_f, hbuf, nullptr, NN);

    for (int l = 0; l < NL; ++l) {
        // x = h @ W_l  (bf16 out, feeds gather)
        k_gemm_mfma<<<gblocks, 256, 0, stream>>>(hbuf, Bhi + (size_t)(1 + l) * 16384,
                                                 Blo + (size_t)(1 + l) * 16384, nullptr,
                                                 nullptr, (__hip_bfloat16*)xb, NN);
        k_agg<<<NN / 4, 256, 0, stream>>>(xb, csr_pack, offsets, counts, bs_f + l * 128, abuf);
        hipMemsetAsync(stats, 0, 256 * 4, stream);
        k_bnred<<<(NN + 255) / 256, 256, 0, stream>>>(abuf, stats);
        k_bnstats<<<1, 128, 0, stream>>>(stats);
        k_bnup<<<(NN * 128) / 256, 256, 0, stream>>>(abuf, stats, gam_f + l * 128, bet_f + l * 128, hbuf);
    }
    k_mlp<<<NN / 4, 256, 0, stream>>>(hbuf, Wm_f, bm_f, d_out, flags);
}

// Round 7
// 660.857 us; speedup vs baseline: 2.6299x; 1.1467x over previous
//
#include <hip/hip_runtime.h>
#include <hip/hip_bf16.h>

#define NN 50000
#define EE 800000
#define HIDD 128
#define NL 4
#define NC 10
#define BN_EPS 1e-5f

typedef __bf16 bf16x8 __attribute__((ext_vector_type(8)));
typedef float f32x4 __attribute__((ext_vector_type(4)));

// ---------------- runtime dtype detection ----------------
// flags[0]: 1 = float inputs are fp32, 0 = bf16
// flags[1]: 1 = edge_index is int64, 0 = int32
__global__ void k_detect(const void* h, const void* ei, int* flags) {
    __shared__ int wild, zeros;
    if (threadIdx.x == 0) { wild = 0; zeros = 0; }
    __syncthreads();
    int t = threadIdx.x;
    const unsigned short* hb = (const unsigned short*)h;
    int lw = 0;
    for (int i = t; i < 4096; i += 256) {
        unsigned short u = hb[i];
        int e = (u >> 7) & 0xFF;
        if ((e >= 0x8F || e == 0) && (u & 0x7FFF) != 0) lw++;
    }
    atomicAdd(&wild, lw);
    const int* ii = (const int*)ei;
    int lz = 0;
    for (int i = t; i < 512; i += 256)
        if (ii[2 * i + 1] == 0) lz++;
    atomicAdd(&zeros, lz);
    __syncthreads();
    if (threadIdx.x == 0) {
        flags[0] = (wild > 256) ? 1 : 0;
        flags[1] = (zeros > 256) ? 1 : 0;
    }
}

__device__ __forceinline__ int edge_at(const void* ei, int i64, long long idx) {
    return i64 ? (int)((const long long*)ei)[idx] : ((const int*)ei)[idx];
}

__global__ void k_cvt(const void* src, float* dst, int n, const int* flags) {
    int i = blockIdx.x * 256 + threadIdx.x;
    if (i >= n) return;
    if (flags[0]) dst[i] = ((const float*)src)[i];
    else          dst[i] = (float)((const __hip_bfloat16*)src)[i];
}

// ---------------- graph preprocessing ----------------

__global__ void k_init_counts(int* counts) {
    int i = blockIdx.x * 256 + threadIdx.x;
    if (i < NN) counts[i] = 1;  // self-loop
}

__global__ void k_count_edges(const void* ei, int* counts, const int* flags) {
    int e = blockIdx.x * 256 + threadIdx.x;
    if (e < EE) {
        int d = edge_at(ei, flags[1], (long long)EE + e);
        if ((unsigned)d < NN) atomicAdd(&counts[d], 1);
    }
}

__global__ void k_dinv(const int* counts, float* dinv) {
    int i = blockIdx.x * 256 + threadIdx.x;
    if (i < NN) dinv[i] = rsqrtf((float)counts[i]);
}

__global__ void k_scan1(const int* counts, int* offsets, int* bsums) {
    __shared__ int sc[256];
    int tid = threadIdx.x;
    int base = blockIdx.x * 1024 + tid * 4;
    int4 c = {0, 0, 0, 0};
    if (base + 3 < NN) {
        c = *(const int4*)(counts + base);
    } else {
        if (base + 0 < NN) c.x = counts[base];
        if (base + 1 < NN) c.y = counts[base + 1];
        if (base + 2 < NN) c.z = counts[base + 2];
        if (base + 3 < NN) c.w = counts[base + 3];
    }
    int s = c.x + c.y + c.z + c.w;
    sc[tid] = s;
    __syncthreads();
    for (int off = 1; off < 256; off <<= 1) {
        int v = (tid >= off) ? sc[tid - off] : 0;
        __syncthreads();
        sc[tid] += v;
        __syncthreads();
    }
    int excl = sc[tid] - s;
    if (base < NN) {
        int4 o;
        o.x = excl; o.y = excl + c.x; o.z = o.y + c.y; o.w = o.z + c.z;
        *(int4*)(offsets + base) = o;
    }
    if (tid == 255) bsums[blockIdx.x] = sc[255];
}

__global__ void k_scan2(int* bsums, int nb) {
    __shared__ int sc[64];
    int tid = threadIdx.x;
    int v = (tid < nb) ? bsums[tid] : 0;
    sc[tid] = v;
    __syncthreads();
    for (int off = 1; off < 64; off <<= 1) {
        int u = (tid >= off) ? sc[tid - off] : 0;
        __syncthreads();
        sc[tid] += u;
        __syncthreads();
    }
    if (tid < nb) bsums[tid] = sc[tid] - v;
}

__global__ void k_scan3(int* offsets, const int* bsums) {
    int base = blockIdx.x * 1024 + threadIdx.x * 4;
    if (base < NN) {
        int add = bsums[blockIdx.x];
        int4 o = *(int4*)(offsets + base);
        o.x += add; o.y += add; o.z += add; o.w += add;
        *(int4*)(offsets + base) = o;
    }
}

__global__ void k_fill_edges(const void* ei, const int* offsets, int* cursor,
                             const float* dinv, int2* csr_pack, const int* flags) {
    int e = blockIdx.x * 256 + threadIdx.x;
    if (e >= EE) return;
    int i64 = flags[1];
    int s = edge_at(ei, i64, e);
    int d = edge_at(ei, i64, (long long)EE + e);
    if ((unsigned)s >= NN || (unsigned)d >= NN) return;
    int pos = offsets[d] + atomicAdd(&cursor[d], 1);
    int2 p; p.x = s; p.y = __float_as_int(dinv[s] * dinv[d]);
    csr_pack[pos] = p;
}

__global__ void k_fill_loops(const int* offsets, int* cursor, const float* dinv,
                             int2* csr_pack) {
    int i = blockIdx.x * 256 + threadIdx.x;
    if (i >= NN) return;
    int pos = offsets[i] + atomicAdd(&cursor[i], 1);
    float di = dinv[i];
    int2 p; p.x = i; p.y = __float_as_int(di * di);
    csr_pack[pos] = p;
}

// ---------------- weight packing into MFMA B-fragment order (hi/lo planes) ----------------
__global__ void k_pack(const float* Wemb, const float* Ws, __bf16* Bhi, __bf16* Blo) {
    int idx = blockIdx.x * 256 + threadIdx.x;
    if (idx >= 5 * 16384) return;
    int m = idx >> 14, r = idx & 16383;
    int kt = r >> 12, nt = (r >> 9) & 7, lane = (r >> 3) & 63, j = r & 7;
    int k = kt * 32 + (lane >> 4) * 8 + j;
    int n = nt * 16 + (lane & 15);
    const float* W = (m == 0) ? Wemb : (Ws + (size_t)(m - 1) * 16384);
    float w = W[k * 128 + n];
    __bf16 hi = (__bf16)w;
    Bhi[idx] = hi;
    Blo[idx] = (__bf16)(w - (float)hi);
}

// ---------------- MFMA GEMM ----------------
// mode 0: A = raw network input (fp32 or bf16 per flags[0]); bias added in epilogue; fp32 C out.
// mode 1: A = fp32 hbuf as-is; bf16 Cb out.
// mode 2: A-row = hbuf + relu(abuf*S + T)  (fused BN+ReLU+residual of previous layer);
//         writes the new h row back to Hout; bf16 Cb out.
__global__ __launch_bounds__(256) void k_gemm_mfma(const void* __restrict__ Araw,
                                                   const float* __restrict__ Aagg,
                                                   const float* __restrict__ ST,
                                                   const __bf16* __restrict__ Bhi,
                                                   const __bf16* __restrict__ Blo,
                                                   const float* __restrict__ bias,
                                                   float* __restrict__ C,
                                                   __hip_bfloat16* __restrict__ Cb,
                                                   float* __restrict__ Hout,
                                                   int M, int mode, const int* flags) {
    __shared__ __bf16 a_hi[64][136];
    __shared__ __bf16 a_lo[64][136];
    int tid = threadIdx.x;
    int r0 = blockIdx.x * 64;
    int cq = tid & 31;   // float4 index within row
    int rb = tid >> 5;   // 0..7
    int cb = cq * 4;
    float4 S4, T4;
    if (mode == 2) {
        S4 = *(const float4*)(ST + cb);
        T4 = *(const float4*)(ST + 128 + cb);
    }
    int afp32 = (mode == 0) ? flags[0] : 1;
#pragma unroll
    for (int p = 0; p < 8; ++p) {
        int r = rb + p * 8;
        int gr = r0 + r;
        float f[4] = {0.f, 0.f, 0.f, 0.f};
        if (gr < M) {
            if (mode == 0) {
                if (afp32) {
                    float4 v = ((const float4*)Araw)[(size_t)gr * 32 + cq];
                    f[0] = v.x; f[1] = v.y; f[2] = v.z; f[3] = v.w;
                } else {
                    const __hip_bfloat16* ab = (const __hip_bfloat16*)Araw + (size_t)gr * 128 + cb;
#pragma unroll
                    for (int t = 0; t < 4; ++t) f[t] = (float)ab[t];
                }
            } else {
                float4 v = *(const float4*)((const float*)Araw + (size_t)gr * 128 + cb);
                if (mode == 2) {
                    float4 a = *(const float4*)(Aagg + (size_t)gr * 128 + cb);
                    v.x += fmaxf(fmaf(a.x, S4.x, T4.x), 0.f);
                    v.y += fmaxf(fmaf(a.y, S4.y, T4.y), 0.f);
                    v.z += fmaxf(fmaf(a.z, S4.z, T4.z), 0.f);
                    v.w += fmaxf(fmaf(a.w, S4.w, T4.w), 0.f);
                    *(float4*)(Hout + (size_t)gr * 128 + cb) = v;
                }
                f[0] = v.x; f[1] = v.y; f[2] = v.z; f[3] = v.w;
            }
        }
#pragma unroll
        for (int t = 0; t < 4; ++t) {
            __bf16 hi = (__bf16)f[t];
            a_hi[r][cb + t] = hi;
            a_lo[r][cb + t] = (__bf16)(f[t] - (float)hi);
        }
    }
    __syncthreads();
    int lane = tid & 63, wave = tid >> 6;
    int quad = lane >> 4, l15 = lane & 15;
    int rw = wave * 16;
    f32x4 acc[8];
#pragma unroll
    for (int nt = 0; nt < 8; ++nt) acc[nt] = (f32x4){0.f, 0.f, 0.f, 0.f};
#pragma unroll
    for (int kt = 0; kt < 4; ++kt) {
        int k0 = kt * 32 + quad * 8;
        bf16x8 ah = *(const bf16x8*)&a_hi[rw + l15][k0];
        bf16x8 al = *(const bf16x8*)&a_lo[rw + l15][k0];
#pragma unroll
        for (int nt = 0; nt < 8; ++nt) {
            size_t boff = (((size_t)(kt * 8 + nt) * 64 + lane) * 8);
            bf16x8 bh = *(const bf16x8*)(Bhi + boff);
            bf16x8 bl = *(const bf16x8*)(Blo + boff);
            acc[nt] = __builtin_amdgcn_mfma_f32_16x16x32_bf16(ah, bh, acc[nt], 0, 0, 0);
            acc[nt] = __builtin_amdgcn_mfma_f32_16x16x32_bf16(al, bh, acc[nt], 0, 0, 0);
            acc[nt] = __builtin_amdgcn_mfma_f32_16x16x32_bf16(ah, bl, acc[nt], 0, 0, 0);
        }
    }
#pragma unroll
    for (int nt = 0; nt < 8; ++nt) {
        int col = nt * 16 + l15;
        float badd = bias ? bias[col] : 0.f;
#pragma unroll
        for (int reg = 0; reg < 4; ++reg) {
            int gr = r0 + rw + quad * 4 + reg;
            if (gr < M) {
                float v = acc[nt][reg] + badd;
                if (Cb) Cb[(size_t)gr * 128 + col] = __float2bfloat16(v);
                else    C[(size_t)gr * 128 + col] = v;
            }
        }
    }
}

// ---------------- aggregation: out[d] = sum_{e: dst=d} x[src_e]*w_e + bias ----------------
// x rows bf16 (256 B). One wave per dst node; 4-edge unroll for 4x in-flight loads.
__global__ __launch_bounds__(256) void k_agg(const unsigned int* __restrict__ xb,
                                             const int2* __restrict__ csr_pack,
                                             const int* __restrict__ offsets,
                                             const int* __restrict__ counts,
                                             const float* __restrict__ bias,
                                             float* __restrict__ out) {
    int node = blockIdx.x * 4 + (threadIdx.x >> 6);
    int lane = threadIdx.x & 63;
    int start = offsets[node], cnt = counts[node];
    float a0 = 0.f, a1 = 0.f, b0 = 0.f, b1 = 0.f;
    float c0 = 0.f, c1 = 0.f, d0 = 0.f, d1 = 0.f;
    for (int base = 0; base < cnt; base += 64) {
        int2 p = make_int2(0, 0);
        if (base + lane < cnt) p = csr_pack[start + base + lane];
        int m = min(64, cnt - base);
        int j = 0;
        for (; j + 4 <= m; j += 4) {
            int s0 = __shfl(p.x, j);
            float w0 = __int_as_float(__shfl(p.y, j));
            int s1 = __shfl(p.x, j + 1);
            float w1 = __int_as_float(__shfl(p.y, j + 1));
            int s2 = __shfl(p.x, j + 2);
            float w2 = __int_as_float(__shfl(p.y, j + 2));
            int s3 = __shfl(p.x, j + 3);
            float w3 = __int_as_float(__shfl(p.y, j + 3));
            unsigned int u0 = xb[s0 * 64 + lane];
            unsigned int u1 = xb[s1 * 64 + lane];
            unsigned int u2 = xb[s2 * 64 + lane];
            unsigned int u3 = xb[s3 * 64 + lane];
            a0 = fmaf(__uint_as_float(u0 << 16), w0, a0);
            a1 = fmaf(__uint_as_float(u0 & 0xFFFF0000u), w0, a1);
            b0 = fmaf(__uint_as_float(u1 << 16), w1, b0);
            b1 = fmaf(__uint_as_float(u1 & 0xFFFF0000u), w1, b1);
            c0 = fmaf(__uint_as_float(u2 << 16), w2, c0);
            c1 = fmaf(__uint_as_float(u2 & 0xFFFF0000u), w2, c1);
            d0 = fmaf(__uint_as_float(u3 << 16), w3, d0);
            d1 = fmaf(__uint_as_float(u3 & 0xFFFF0000u), w3, d1);
        }
        for (; j < m; ++j) {
            int s0 = __shfl(p.x, j);
            float w0 = __int_as_float(__shfl(p.y, j));
            unsigned int u0 = xb[s0 * 64 + lane];
            a0 = fmaf(__uint_as_float(u0 << 16), w0, a0);
            a1 = fmaf(__uint_as_float(u0 & 0xFFFF0000u), w0, a1);
        }
    }
    float2 o;
    o.x = (a0 + b0) + (c0 + d0) + bias[lane * 2];
    o.y = (a1 + b1) + (c1 + d1) + bias[lane * 2 + 1];
    ((float2*)(out + (size_t)node * 128))[lane] = o;
}

// ---------------- batchnorm stats ----------------

__global__ __launch_bounds__(256) void k_bnred(const float* agg, float* stats) {
    __shared__ float ls[256], lss[256];
    int tid = threadIdx.x;
    int col = tid & 127;
    int r = blockIdx.x * 256 + (tid >> 7);
    int rend = min(NN, (int)(blockIdx.x + 1) * 256);
    float s = 0.f, ss = 0.f;
    for (; r < rend; r += 2) {
        float v = agg[(size_t)r * 128 + col];
        s += v;
        ss += v * v;
    }
    ls[tid] = s;
    lss[tid] = ss;
    __syncthreads();
    if (tid < 128) atomicAdd(&stats[col], ls[tid] + ls[tid + 128]);
    else atomicAdd(&stats[128 + col], lss[tid - 128] + lss[tid]);
}

// stats -> affine: h' = h + relu(a*S + T)
__global__ void k_bnstats(float* stats, const float* gamma, const float* beta) {
    int c = threadIdx.x;  // 128 threads
    float mu = stats[c] * (1.f / NN);
    float var = stats[128 + c] * (1.f / NN) - mu * mu;
    var = fmaxf(var, 0.f);
    float rs = rsqrtf(var + BN_EPS);
    float S = rs * gamma[c];
    stats[c] = S;
    stats[128 + c] = beta[c] - mu * S;
}

// ---------------- fused final BN + MLP: out[N x 10] ----------------
// wave = 4 nodes x 16 lanes; h4 = h3 + relu(a*S+T) computed on the fly.
__global__ __launch_bounds__(256) void k_mlp_fused(const float* __restrict__ h,
                                                   const float* __restrict__ agg,
                                                   const float* __restrict__ ST,
                                                   const float* __restrict__ Wm,
                                                   const float* __restrict__ bm,
                                                   void* __restrict__ out,
                                                   const int* __restrict__ flags) {
    __shared__ float Wt[10][132];  // transposed W: Wt[cls][k]
    int tid = threadIdx.x;
    for (int i = tid; i < 1280; i += 256) {
        int cls = i >> 7, k = i & 127;
        Wt[cls][k] = Wm[k * 10 + cls];
    }
    __syncthreads();
    int wave = tid >> 6, lane = tid & 63;
    int nl = lane >> 4, c = lane & 15;
    int node = blockIdx.x * 16 + wave * 4 + nl;
    size_t rowo = (size_t)node * 128 + c * 8;
    float4 h0 = *(const float4*)(h + rowo);
    float4 h1 = *(const float4*)(h + rowo + 4);
    float4 a0 = *(const float4*)(agg + rowo);
    float4 a1 = *(const float4*)(agg + rowo + 4);
    float4 S0 = *(const float4*)(ST + c * 8);
    float4 S1 = *(const float4*)(ST + c * 8 + 4);
    float4 T0 = *(const float4*)(ST + 128 + c * 8);
    float4 T1 = *(const float4*)(ST + 128 + c * 8 + 4);
    float hv[8];
    hv[0] = h0.x + fmaxf(fmaf(a0.x, S0.x, T0.x), 0.f);
    hv[1] = h0.y + fmaxf(fmaf(a0.y, S0.y, T0.y), 0.f);
    hv[2] = h0.z + fmaxf(fmaf(a0.z, S0.z, T0.z), 0.f);
    hv[3] = h0.w + fmaxf(fmaf(a0.w, S0.w, T0.w), 0.f);
    hv[4] = h1.x + fmaxf(fmaf(a1.x, S1.x, T1.x), 0.f);
    hv[5] = h1.y + fmaxf(fmaf(a1.y, S1.y, T1.y), 0.f);
    hv[6] = h1.z + fmaxf(fmaf(a1.z, S1.z, T1.z), 0.f);
    hv[7] = h1.w + fmaxf(fmaf(a1.w, S1.w, T1.w), 0.f);
    float p[10];
#pragma unroll
    for (int cls = 0; cls < 10; ++cls) {
        float4 w0 = *(const float4*)&Wt[cls][c * 8];
        float4 w1 = *(const float4*)&Wt[cls][c * 8 + 4];
        float s = fmaf(hv[0], w0.x, fmaf(hv[1], w0.y, fmaf(hv[2], w0.z, hv[3] * w0.w)));
        s = fmaf(hv[4], w1.x, fmaf(hv[5], w1.y, fmaf(hv[6], w1.z, fmaf(hv[7], w1.w, s))));
        p[cls] = s;
    }
#pragma unroll
    for (int m = 1; m < 16; m <<= 1)
#pragma unroll
        for (int cls = 0; cls < 10; ++cls)
            p[cls] += __shfl_xor(p[cls], m);
    if (c == 0) {
        if (flags[0]) {
            float* o = (float*)out;
            for (int cls = 0; cls < 10; ++cls) o[node * 10 + cls] = p[cls] + bm[cls];
        } else {
            __hip_bfloat16* o = (__hip_bfloat16*)out;
            for (int cls = 0; cls < 10; ++cls)
                o[node * 10 + cls] = __float2bfloat16(p[cls] + bm[cls]);
        }
    }
}

// ---------------- orchestration ----------------

extern "C" void kernel_launch(void* const* d_in, const int* in_sizes, int n_in,
                              void* d_out, int out_size, void* d_ws, size_t ws_size,
                              hipStream_t stream) {
    const void* h_in = d_in[0];
    const void* ei   = d_in[1];
    const void* Wemb = d_in[3];
    const void* bemb = d_in[4];
    const void* Ws   = d_in[5];
    const void* bs   = d_in[6];
    const void* gam  = d_in[7];
    const void* bet  = d_in[8];
    const void* Wm   = d_in[9];
    const void* bm   = d_in[10];

    char* ws = (char*)d_ws;
    size_t off = 0;
    auto alloc = [&](size_t bytes) -> void* {
        void* p = ws + off;
        off = (off + bytes + 255) & ~(size_t)255;
        return p;
    };
    float* hbuf    = (float*)alloc((size_t)NN * 128 * 4);
    float* abuf    = (float*)alloc((size_t)NN * 128 * 4);
    unsigned int* xb = (unsigned int*)alloc((size_t)NN * 64 * 4);  // bf16 x, 256 B/row
    int* counts    = (int*)alloc((size_t)NN * 4);
    int* offsets   = (int*)alloc((size_t)(NN + 1024) * 4);
    int* cursor    = (int*)alloc((size_t)NN * 4);
    int* bsums     = (int*)alloc(64 * 4);
    float* dinv    = (float*)alloc((size_t)NN * 4);
    float* stats   = (float*)alloc(256 * 4);
    int2* csr_pack = (int2*)alloc((size_t)(EE + NN) * 8);
    int* flags     = (int*)alloc(64);
    float* Wemb_f  = (float*)alloc(16384 * 4);
    float* Ws_f    = (float*)alloc(65536 * 4);
    float* bemb_f  = (float*)alloc(128 * 4);
    float* bs_f    = (float*)alloc(512 * 4);
    float* gam_f   = (float*)alloc(512 * 4);
    float* bet_f   = (float*)alloc(512 * 4);
    float* Wm_f    = (float*)alloc(1280 * 4);
    float* bm_f    = (float*)alloc(16 * 4);
    __bf16* Bhi    = (__bf16*)alloc((size_t)5 * 16384 * 2);
    __bf16* Blo    = (__bf16*)alloc((size_t)5 * 16384 * 2);

    k_detect<<<1, 256, 0, stream>>>(h_in, ei, flags);

    k_cvt<<<64, 256, 0, stream>>>(Wemb, Wemb_f, 16384, flags);
    k_cvt<<<256, 256, 0, stream>>>(Ws, Ws_f, 65536, flags);
    k_cvt<<<1, 256, 0, stream>>>(bemb, bemb_f, 128, flags);
    k_cvt<<<2, 256, 0, stream>>>(bs, bs_f, 512, flags);
    k_cvt<<<2, 256, 0, stream>>>(gam, gam_f, 512, flags);
    k_cvt<<<2, 256, 0, stream>>>(bet, bet_f, 512, flags);
    k_cvt<<<5, 256, 0, stream>>>(Wm, Wm_f, 1280, flags);
    k_cvt<<<1, 256, 0, stream>>>(bm, bm_f, 10, flags);

    k_pack<<<(5 * 16384 + 255) / 256, 256, 0, stream>>>(Wemb_f, Ws_f, Bhi, Blo);

    hipMemsetAsync(cursor, 0, (size_t)NN * 4, stream);
    k_init_counts<<<(NN + 255) / 256, 256, 0, stream>>>(counts);
    k_count_edges<<<(EE + 255) / 256, 256, 0, stream>>>(ei, counts, flags);
    k_dinv<<<(NN + 255) / 256, 256, 0, stream>>>(counts, dinv);
    int nb = (NN + 1023) / 1024;  // 49
    k_scan1<<<nb, 256, 0, stream>>>(counts, offsets, bsums);
    k_scan2<<<1, 64, 0, stream>>>(bsums, nb);
    k_scan3<<<nb, 256, 0, stream>>>(offsets, bsums);
    k_fill_edges<<<(EE + 255) / 256, 256, 0, stream>>>(ei, offsets, cursor, dinv, csr_pack, flags);
    k_fill_loops<<<(NN + 255) / 256, 256, 0, stream>>>(offsets, cursor, dinv, csr_pack);

    int gblocks = (NN + 63) / 64;  // 782
    // embedding: hbuf = input @ W_emb + b_emb  (fp32 out, raw input staged directly)
    k_gemm_mfma<<<gblocks, 256, 0, stream>>>(h_in, nullptr, nullptr, Bhi, Blo, bemb_f,
                                             hbuf, nullptr, nullptr, NN, 0, flags);

    for (int l = 0; l < NL; ++l) {
        if (l == 0) {
            k_gemm_mfma<<<gblocks, 256, 0, stream>>>(hbuf, nullptr, nullptr,
                                                     Bhi + (size_t)1 * 16384, Blo + (size_t)1 * 16384,
                                                     nullptr, nullptr, (__hip_bfloat16*)xb,
                                                     nullptr, NN, 1, flags);
        } else {
            // fused: h = h + relu(abuf*S+T) (prev layer BN), then x = h @ W_l
            k_gemm_mfma<<<gblocks, 256, 0, stream>>>(hbuf, abuf, stats,
                                                     Bhi + (size_t)(1 + l) * 16384,
                                                     Blo + (size_t)(1 + l) * 16384,
                                                     nullptr, nullptr, (__hip_bfloat16*)xb,
                                                     hbuf, NN, 2, flags);
        }
        k_agg<<<NN / 4, 256, 0, stream>>>(xb, csr_pack, offsets, counts, bs_f + l * 128, abuf);
        hipMemsetAsync(stats, 0, 256 * 4, stream);
        k_bnred<<<(NN + 255) / 256, 256, 0, stream>>>(abuf, stats);
        k_bnstats<<<1, 128, 0, stream>>>(stats, gam_f + l * 128, bet_f + l * 128);
    }
    // final: h4 = h3 + relu(abuf3*S+T); out = h4 @ W_mlp + b_mlp
    k_mlp_fused<<<NN / 16, 256, 0, stream>>>(hbuf, abuf, stats, Wm_f, bm_f, d_out, flags);
}